// Round 1
// baseline (3920.630 us; speedup 1.0000x reference)
//
#include <hip/hip_runtime.h>

typedef __attribute__((ext_vector_type(8))) short sh8;
typedef __attribute__((ext_vector_type(8))) __bf16 bf8v;
typedef __attribute__((ext_vector_type(4))) float f4v;

__device__ __forceinline__ unsigned short f2bf(float f) {
  unsigned u = __builtin_bit_cast(unsigned, f);
  u += 0x7fffu + ((u >> 16) & 1u);
  return (unsigned short)(u >> 16);
}
__device__ __forceinline__ float bf2f(unsigned short h) {
  unsigned u = ((unsigned)h) << 16;
  return __builtin_bit_cast(float, u);
}

// ---------------- cast x -> bf16 (vectorized) ----------------
__global__ __launch_bounds__(256) void cast_kernel(const float* __restrict__ in,
                                                   unsigned short* __restrict__ out) {
  const int idx = (blockIdx.x * 256 + threadIdx.x) * 4;
  const float4 v = *(const float4*)(in + idx);
  ushort4 o;
  o.x = f2bf(v.x); o.y = f2bf(v.y); o.z = f2bf(v.z); o.w = f2bf(v.w);
  *(ushort4*)(out + idx) = o;
}

// ---------------- transpose + cast weights: in[R][C] -> out[C][R] bf16 ----------------
__global__ __launch_bounds__(256) void transpose_cast_kernel(const float* __restrict__ in,
                                                             unsigned short* __restrict__ out,
                                                             int R, int C) {
  __shared__ float tile[32][33];
  const int c0 = blockIdx.x * 32, r0 = blockIdx.y * 32;
  const int tx = threadIdx.x, ty = threadIdx.y;
#pragma unroll
  for (int i = 0; i < 4; ++i)
    tile[ty + 8 * i][tx] = in[(size_t)(r0 + ty + 8 * i) * C + c0 + tx];
  __syncthreads();
#pragma unroll
  for (int i = 0; i < 4; ++i)
    out[(size_t)(c0 + ty + 8 * i) * R + r0 + tx] = f2bf(tile[tx][ty + 8 * i]);
}

// ---------------- bf16 MFMA GEMM: C[M][N] = A[M][K] @ Bt[N][K]^T ----------------
// MODE 0: QKV epilogue -> scatter to q/k/v [B*H][N][64] bf16, Q scaled by 0.125
// MODE 1: proj epilogue -> out[r*N+c] = acc + bias[c]  (fp32)
template <int MODE>
__global__ __launch_bounds__(256) void gemm_bf16_kernel(
    const unsigned short* __restrict__ A,   // [M][K] bf16
    const unsigned short* __restrict__ Bt,  // [N][K] bf16
    int M, int N, int K,
    unsigned short* __restrict__ q_out, unsigned short* __restrict__ k_out,
    unsigned short* __restrict__ v_out,
    const float* __restrict__ bias, float* __restrict__ c_out) {
  constexpr int BM = 128, BN = 128, BK = 32, LDT = 40;
  __shared__ alignas(16) unsigned short As[BM * LDT];
  __shared__ alignas(16) unsigned short Bs[BN * LDT];
  const int tid = threadIdx.x;
  const int lane = tid & 63;
  const int wave = tid >> 6;            // 4 waves, 2x2
  const int wr = (wave >> 1) * 64;
  const int wc = (wave & 1) * 64;
  const int bm = blockIdx.x * BM;
  const int bn = blockIdx.y * BN;
  const int fr = lane & 15;
  const int kq = lane >> 4;

  f4v acc[4][4] = {};

  const int arow = tid >> 2;            // 0..63
  const int aseg = tid & 3;             // 4 x 8 bf16 = 32 cols

  for (int k0 = 0; k0 < K; k0 += BK) {
    __syncthreads();
#pragma unroll
    for (int it = 0; it < 2; ++it) {
      const int row = it * 64 + arow;
      const unsigned short* pa = A + (size_t)(bm + row) * K + k0 + aseg * 8;
      const unsigned short* pb = Bt + (size_t)(bn + row) * K + k0 + aseg * 8;
      *(sh8*)&As[row * LDT + aseg * 8] = *(const sh8*)pa;
      *(sh8*)&Bs[row * LDT + aseg * 8] = *(const sh8*)pb;
    }
    __syncthreads();
    bf8v af[4], bfv[4];
#pragma unroll
    for (int m = 0; m < 4; ++m)
      af[m] = __builtin_bit_cast(bf8v, *(const sh8*)&As[(wr + m * 16 + fr) * LDT + kq * 8]);
#pragma unroll
    for (int n = 0; n < 4; ++n)
      bfv[n] = __builtin_bit_cast(bf8v, *(const sh8*)&Bs[(wc + n * 16 + fr) * LDT + kq * 8]);
#pragma unroll
    for (int m = 0; m < 4; ++m)
#pragma unroll
      for (int n = 0; n < 4; ++n)
        acc[m][n] = __builtin_amdgcn_mfma_f32_16x16x32_bf16(af[m], bfv[n], acc[m][n], 0, 0, 0);
  }

#pragma unroll
  for (int m = 0; m < 4; ++m) {
#pragma unroll
    for (int n = 0; n < 4; ++n) {
#pragma unroll
      for (int i = 0; i < 4; ++i) {
        const int r = bm + wr + m * 16 + kq * 4 + i;
        const int c = bn + wc + n * 16 + fr;
        const float val = acc[m][n][i];
        if (MODE == 0) {
          const int b = r >> 11, nidx = r & 2047;
          const int which = c >> 10, rem = c & 1023;
          const int h = rem >> 6, d = rem & 63;
          const size_t off = ((size_t)((b * 16 + h) * 2048 + nidx)) * 64 + d;
          if (which == 0)      q_out[off] = f2bf(val * 0.125f);
          else if (which == 1) k_out[off] = f2bf(val);
          else                 v_out[off] = f2bf(val);
        } else {
          c_out[(size_t)r * N + c] = val + bias[c];
        }
      }
    }
  }
}

// ---------------- causal flash attention (VALU, fp32 accum) ----------------
// Q/K/V: [B*H][2048][64] bf16 (Q pre-scaled). O: [B*2048][1024] bf16.
__global__ __launch_bounds__(512) void attn_kernel(
    const unsigned short* __restrict__ Q, const unsigned short* __restrict__ Kg,
    const unsigned short* __restrict__ Vg, unsigned short* __restrict__ O) {
  __shared__ float Ks[64][66];
  __shared__ float Vs[64][66];
  __shared__ float Qs[32][68];
  __shared__ float Ps[32][68];
  const int tid = threadIdx.x;
  const int lane = tid & 63;
  const int w = tid >> 6;               // 8 waves
  const int bh = blockIdx.y;
  const int b = bh >> 4, h = bh & 15;
  const int r0 = blockIdx.x * 32;
  const unsigned short* Qb = Q + (size_t)bh * 2048 * 64;
  const unsigned short* Kb = Kg + (size_t)bh * 2048 * 64;
  const unsigned short* Vb = Vg + (size_t)bh * 2048 * 64;

  // stage 32 q rows (fp32)
  if (tid < 256) {
    const int row = tid >> 3, seg = tid & 7;
    const sh8 q8 = *(const sh8*)&Qb[(size_t)(r0 + row) * 64 + seg * 8];
#pragma unroll
    for (int t = 0; t < 8; ++t) Qs[row][seg * 8 + t] = bf2f((unsigned short)q8[t]);
  }

  float mreg[4] = {-1e30f, -1e30f, -1e30f, -1e30f};
  float lreg[4] = {0.f, 0.f, 0.f, 0.f};
  float oreg[4] = {0.f, 0.f, 0.f, 0.f};

  const int ntiles = r0 / 64 + 1;
  for (int j = 0; j < ntiles; ++j) {
    __syncthreads();
    {
      const int row = tid >> 3, seg = tid & 7;   // 512 threads = 64 rows x 8 segs
      const size_t goff = (size_t)(j * 64 + row) * 64 + seg * 8;
      const sh8 k8 = *(const sh8*)&Kb[goff];
      const sh8 v8 = *(const sh8*)&Vb[goff];
#pragma unroll
      for (int t = 0; t < 4; ++t) {
        *(float2*)&Ks[row][seg * 8 + 2 * t] =
            make_float2(bf2f((unsigned short)k8[2 * t]), bf2f((unsigned short)k8[2 * t + 1]));
        *(float2*)&Vs[row][seg * 8 + 2 * t] =
            make_float2(bf2f((unsigned short)v8[2 * t]), bf2f((unsigned short)v8[2 * t + 1]));
      }
    }
    __syncthreads();

    // QK^T: 4 interleaved rows per wave, K row per lane
    float s4[4] = {0.f, 0.f, 0.f, 0.f};
#pragma unroll
    for (int dg = 0; dg < 16; ++dg) {
      const float kv0 = Ks[lane][dg * 4 + 0];
      const float kv1 = Ks[lane][dg * 4 + 1];
      const float kv2 = Ks[lane][dg * 4 + 2];
      const float kv3 = Ks[lane][dg * 4 + 3];
#pragma unroll
      for (int i = 0; i < 4; ++i) {
        const float4 q4 = *(const float4*)&Qs[w + 8 * i][dg * 4];
        s4[i] += q4.x * kv0 + q4.y * kv1 + q4.z * kv2 + q4.w * kv3;
      }
    }

    // online softmax per row (wave-uniform act guard)
#pragma unroll
    for (int i = 0; i < 4; ++i) {
      const int row = r0 + w + 8 * i;
      const bool act = (j * 64 <= row);
      float p = 0.f, alpha = 1.f;
      if (act) {
        float s = s4[i];
        if (j * 64 + lane > row) s = -1e30f;
        float mx = s;
#pragma unroll
        for (int off = 32; off; off >>= 1) mx = fmaxf(mx, __shfl_xor(mx, off));
        const float mn = fmaxf(mreg[i], mx);
        p = __expf(s - mn);
        float sm = p;
#pragma unroll
        for (int off = 32; off; off >>= 1) sm += __shfl_xor(sm, off);
        alpha = __expf(mreg[i] - mn);
        lreg[i] = lreg[i] * alpha + sm;
        mreg[i] = mn;
      }
      Ps[w + 8 * i][lane] = p;
      oreg[i] *= alpha;
    }

    // PV: lane owns output dim d=lane
#pragma unroll
    for (int kg = 0; kg < 16; ++kg) {
      const float vv0 = Vs[kg * 4 + 0][lane];
      const float vv1 = Vs[kg * 4 + 1][lane];
      const float vv2 = Vs[kg * 4 + 2][lane];
      const float vv3 = Vs[kg * 4 + 3][lane];
#pragma unroll
      for (int i = 0; i < 4; ++i) {
        const float4 p4 = *(const float4*)&Ps[w + 8 * i][kg * 4];
        oreg[i] += p4.x * vv0 + p4.y * vv1 + p4.z * vv2 + p4.w * vv3;
      }
    }
  }

#pragma unroll
  for (int i = 0; i < 4; ++i) {
    const int row = r0 + w + 8 * i;
    const float val = oreg[i] / lreg[i];
    O[((size_t)(b * 2048 + row)) * 1024 + h * 64 + lane] = f2bf(val);
  }
}

extern "C" void kernel_launch(void* const* d_in, const int* in_sizes, int n_in,
                              void* d_out, int out_size, void* d_ws, size_t ws_size,
                              hipStream_t stream) {
  const float* x      = (const float*)d_in[0];
  const float* qkv_w  = (const float*)d_in[1];
  const float* proj_w = (const float*)d_in[2];
  const float* proj_b = (const float*)d_in[3];
  float* out = (float*)d_out;

  unsigned short* ws = (unsigned short*)d_ws;
  const size_t NE = (size_t)8192 * 1024;        // 8,388,608
  unsigned short* xb     = ws;                  // x bf16 [8192][1024]; reused as attn out
  unsigned short* wqkvT  = xb + NE;             // [3072][1024]
  unsigned short* wprojT = wqkvT + (size_t)3072 * 1024;   // [1024][1024]
  unsigned short* qb     = wprojT + (size_t)1024 * 1024;  // [64][2048][64]
  unsigned short* kb     = qb + NE;
  unsigned short* vb     = kb + NE;
  unsigned short* ab     = xb;                  // attn output reuses xb (xb dead after QKV GEMM)

  cast_kernel<<<8192, 256, 0, stream>>>(x, xb);
  transpose_cast_kernel<<<dim3(96, 32), dim3(32, 8), 0, stream>>>(qkv_w, wqkvT, 1024, 3072);
  transpose_cast_kernel<<<dim3(32, 32), dim3(32, 8), 0, stream>>>(proj_w, wprojT, 1024, 1024);

  gemm_bf16_kernel<0><<<dim3(64, 24), 256, 0, stream>>>(
      xb, wqkvT, 8192, 3072, 1024, qb, kb, vb, nullptr, nullptr);

  attn_kernel<<<dim3(64, 64), 512, 0, stream>>>(qb, kb, vb, ab);

  gemm_bf16_kernel<1><<<dim3(64, 8), 256, 0, stream>>>(
      ab, wprojT, 8192, 1024, 1024, nullptr, nullptr, nullptr, proj_b, out);
}

// Round 2
// 356.395 us; speedup vs baseline: 11.0008x; 11.0008x over previous
//
#include <hip/hip_runtime.h>

typedef __attribute__((ext_vector_type(8))) short sh8;
typedef __attribute__((ext_vector_type(8))) __bf16 bf8v;
typedef __attribute__((ext_vector_type(4))) float f4v;

__device__ __forceinline__ unsigned short f2bf(float f) {
  unsigned u = __builtin_bit_cast(unsigned, f);
  u += 0x7fffu + ((u >> 16) & 1u);
  return (unsigned short)(u >> 16);
}
__device__ __forceinline__ float bf2f(unsigned short h) {
  unsigned u = ((unsigned)h) << 16;
  return __builtin_bit_cast(float, u);
}

// async global->LDS, 16B per lane; LDS dest = wave-uniform base + lane*16
__device__ __forceinline__ void glds16(const unsigned short* g, unsigned short* l) {
  __builtin_amdgcn_global_load_lds((const __attribute__((address_space(1))) void*)g,
                                   (__attribute__((address_space(3))) void*)l, 16, 0, 0);
}

// ---------------- cast x -> bf16 (vectorized) ----------------
__global__ __launch_bounds__(256) void cast_kernel(const float* __restrict__ in,
                                                   unsigned short* __restrict__ out) {
  const int idx = (blockIdx.x * 256 + threadIdx.x) * 4;
  const float4 v = *(const float4*)(in + idx);
  ushort4 o;
  o.x = f2bf(v.x); o.y = f2bf(v.y); o.z = f2bf(v.z); o.w = f2bf(v.w);
  *(ushort4*)(out + idx) = o;
}

// ---------------- transpose + cast weights: in[R][C] -> out[C][R] bf16 ----------------
__global__ __launch_bounds__(256) void transpose_cast_kernel(const float* __restrict__ in,
                                                             unsigned short* __restrict__ out,
                                                             int R, int C) {
  __shared__ float tile[32][33];
  const int c0 = blockIdx.x * 32, r0 = blockIdx.y * 32;
  const int tx = threadIdx.x, ty = threadIdx.y;
#pragma unroll
  for (int i = 0; i < 4; ++i)
    tile[ty + 8 * i][tx] = in[(size_t)(r0 + ty + 8 * i) * C + c0 + tx];
  __syncthreads();
#pragma unroll
  for (int i = 0; i < 4; ++i)
    out[(size_t)(c0 + ty + 8 * i) * R + r0 + tx] = f2bf(tile[tx][ty + 8 * i]);
}

// ---------------- bf16 MFMA GEMM (m97 structure): C = A[M][K] @ Bt[N][K]^T ----------
// MODE 0: QKV epilogue -> scatter to q/k/v [B*H][N][64] bf16, Q scaled by 0.125
// MODE 1: proj epilogue -> out[r*N+c] = acc + bias[c]  (fp32)
template <int MODE>
__global__ __launch_bounds__(256) void gemm_bf16_kernel(
    const unsigned short* __restrict__ A,   // [M][K] bf16
    const unsigned short* __restrict__ Bt,  // [N][K] bf16
    int M, int N, int K,
    unsigned short* __restrict__ q_out, unsigned short* __restrict__ k_out,
    unsigned short* __restrict__ v_out,
    const float* __restrict__ bias, float* __restrict__ c_out) {
  constexpr int BM = 128, BN = 128, BK = 32;
  __shared__ alignas(16) unsigned short As[BM * 32];
  __shared__ alignas(16) unsigned short Bs[BN * 32];
  const int tid = threadIdx.x;
  const int lane = tid & 63;
  const int wave = tid >> 6;            // 4 waves, 2x2
  const int wr = (wave >> 1) * 64;
  const int wc = (wave & 1) * 64;
  const int bm = blockIdx.x * BM;
  const int bn = blockIdx.y * BN;
  const int fr = lane & 15;
  const int kq = lane >> 4;

  f4v acc[4][4] = {};

  // staging: each wave loads 2 chunks of 16 rows for A and B.
  // LDS is linear [row][32]; global source column slot pre-swizzled so that
  // LDS content(row, sl) = G[row][(sl ^ (row&3))*8]  (T2-style, both-sides).
  const int r16 = lane >> 2;                 // 0..15 row within chunk
  const int slot = (lane & 3) ^ (r16 & 3);   // swizzled source slot

  for (int k0 = 0; k0 < K; k0 += BK) {
    __syncthreads();
#pragma unroll
    for (int s = 0; s < 2; ++s) {
      const int rbase = wave * 32 + s * 16;
      glds16(&A[(size_t)(bm + rbase + r16) * K + k0 + slot * 8], &As[rbase * 32]);
      glds16(&Bt[(size_t)(bn + rbase + r16) * K + k0 + slot * 8], &Bs[rbase * 32]);
    }
    __syncthreads();   // compiler drains vmcnt(0) before s_barrier
    bf8v af[4], bfv[4];
#pragma unroll
    for (int m = 0; m < 4; ++m) {
      const int row = wr + m * 16 + fr;
      af[m] = __builtin_bit_cast(bf8v, *(const sh8*)&As[row * 32 + ((kq * 8) ^ ((row & 3) << 3))]);
    }
#pragma unroll
    for (int n = 0; n < 4; ++n) {
      const int row = wc + n * 16 + fr;
      bfv[n] = __builtin_bit_cast(bf8v, *(const sh8*)&Bs[row * 32 + ((kq * 8) ^ ((row & 3) << 3))]);
    }
#pragma unroll
    for (int m = 0; m < 4; ++m)
#pragma unroll
      for (int n = 0; n < 4; ++n)
        acc[m][n] = __builtin_amdgcn_mfma_f32_16x16x32_bf16(af[m], bfv[n], acc[m][n], 0, 0, 0);
  }

#pragma unroll
  for (int m = 0; m < 4; ++m) {
#pragma unroll
    for (int n = 0; n < 4; ++n) {
#pragma unroll
      for (int i = 0; i < 4; ++i) {
        const int r = bm + wr + m * 16 + kq * 4 + i;
        const int c = bn + wc + n * 16 + fr;
        const float val = acc[m][n][i];
        if (MODE == 0) {
          const int b = r >> 11, nidx = r & 2047;
          const int which = c >> 10, rem = c & 1023;
          const int h = rem >> 6, d = rem & 63;
          const size_t off = ((size_t)((b * 16 + h) * 2048 + nidx)) * 64 + d;
          if (which == 0)      q_out[off] = f2bf(val * 0.125f);
          else if (which == 1) k_out[off] = f2bf(val);
          else                 v_out[off] = f2bf(val);
        } else {
          c_out[(size_t)r * N + c] = val + bias[c];
        }
      }
    }
  }
}

// ---------------- causal flash attention, MFMA (bf16 in, fp32 accum) -------------
// Q/K/V: [B*H][2048][64] bf16 (Q pre-scaled by 0.125). O: [B*2048][1024] bf16.
// Block: 4 waves; wave w owns 16 q-rows. KV tile = 64 rows.
// All LDS tiles: linear 64-short rows, XOR swizzle col ^= (row&7)<<3 (in shorts).
__global__ __launch_bounds__(256) void attn_kernel(
    const unsigned short* __restrict__ Q, const unsigned short* __restrict__ Kg,
    const unsigned short* __restrict__ Vg, unsigned short* __restrict__ O) {
  __shared__ alignas(16) unsigned short Ks[64 * 64];
  __shared__ alignas(16) unsigned short Vts[64 * 64];     // V transposed: [d][k]
  __shared__ alignas(16) unsigned short Ps[4][16 * 64];   // per-wave P
  const int tid = threadIdx.x;
  const int lane = tid & 63;
  const int w = tid >> 6;
  const int c = lane & 15, g = lane >> 4;
  const int qt = 31 - blockIdx.x;     // long blocks first
  const int bh = blockIdx.y;
  const unsigned short* Qb = Q + (size_t)bh * (2048 * 64);
  const unsigned short* Kb = Kg + (size_t)bh * (2048 * 64);
  const unsigned short* Vb = Vg + (size_t)bh * (2048 * 64);
  const int q0w = qt * 64 + w * 16;

  // Q A-fragments held in registers: row = c, k-elems = 8g+t (+32*ds)
  bf8v qa[2];
#pragma unroll
  for (int ds = 0; ds < 2; ++ds)
    qa[ds] = __builtin_bit_cast(bf8v, *(const sh8*)&Qb[(size_t)(q0w + c) * 64 + 8 * g + 32 * ds]);

  f4v o_acc[4] = {};
  float m_i[4], l_i[4];
#pragma unroll
  for (int i = 0; i < 4; ++i) { m_i[i] = -1e30f; l_i[i] = 0.f; }

  for (int j = 0; j <= qt; ++j) {
    __syncthreads();
    // ---- stage K via global_load_lds, source pre-swizzled (m173 pattern) ----
    {
      const int r8 = lane >> 3;              // row within 8-row chunk == row&7
      const int slot = (lane & 7) ^ r8;
#pragma unroll
      for (int s = 0; s < 2; ++s) {
        const int rbase = w * 16 + s * 8;
        glds16(&Kb[(size_t)(j * 64 + rbase + r8) * 64 + slot * 8], &Ks[rbase * 64]);
      }
    }
    // ---- stage V transposed into Vts[d][k], swizzled writes ----
    {
      const int d = tid & 63;
      const int kp = (tid >> 6) * 2;
#pragma unroll
      for (int p = 0; p < 8; ++p) {
        const int k = p * 8 + kp;            // even
        const unsigned short v0 = Vb[(size_t)(j * 64 + k) * 64 + d];
        const unsigned short v1 = Vb[(size_t)(j * 64 + k + 1) * 64 + d];
        *(unsigned*)&Vts[d * 64 + (k ^ ((d & 7) << 3))] = (unsigned)v0 | ((unsigned)v1 << 16);
      }
    }
    __syncthreads();

    // ---- QK^T: S[16q][64k], 8 MFMAs ----
    f4v s[4] = {};
#pragma unroll
    for (int ds = 0; ds < 2; ++ds)
#pragma unroll
      for (int sub = 0; sub < 4; ++sub) {
        const int row = c + 16 * sub;
        const bf8v kf = __builtin_bit_cast(
            bf8v, *(const sh8*)&Ks[row * 64 + ((8 * g + 32 * ds) ^ ((row & 7) << 3))]);
        s[sub] = __builtin_amdgcn_mfma_f32_16x16x32_bf16(qa[ds], kf, s[sub], 0, 0, 0);
      }

    // ---- causal mask on diagonal tile only ----
    if (j == qt) {
      const int lq = w * 16 + 4 * g;
#pragma unroll
      for (int sub = 0; sub < 4; ++sub)
#pragma unroll
        for (int i = 0; i < 4; ++i)
          if (16 * sub + c > lq + i) s[sub][i] = -1e30f;
    }

    // ---- online softmax (C/D layout: row q = 4g+i, col k = c+16sub) ----
    float alpha[4];
#pragma unroll
    for (int i = 0; i < 4; ++i) {
      float mx = fmaxf(fmaxf(s[0][i], s[1][i]), fmaxf(s[2][i], s[3][i]));
#pragma unroll
      for (int off = 8; off; off >>= 1) mx = fmaxf(mx, __shfl_xor(mx, off));
      const float mn = fmaxf(m_i[i], mx);
      float sm = 0.f;
#pragma unroll
      for (int sub = 0; sub < 4; ++sub) {
        const float p = __expf(s[sub][i] - mn);
        s[sub][i] = p;
        sm += p;
      }
#pragma unroll
      for (int off = 8; off; off >>= 1) sm += __shfl_xor(sm, off);
      alpha[i] = __expf(m_i[i] - mn);
      l_i[i] = l_i[i] * alpha[i] + sm;
      m_i[i] = mn;
    }
#pragma unroll
    for (int dsub = 0; dsub < 4; ++dsub)
#pragma unroll
      for (int i = 0; i < 4; ++i) o_acc[dsub][i] *= alpha[i];

    // ---- P -> LDS (bf16, swizzled); per-wave buffer, same-wave LDS ordering ----
#pragma unroll
    for (int sub = 0; sub < 4; ++sub)
#pragma unroll
      for (int i = 0; i < 4; ++i) {
        const int row = 4 * g + i;
        Ps[w][row * 64 + ((c + 16 * sub) ^ ((row & 7) << 3))] = f2bf(s[sub][i]);
      }
    asm volatile("s_waitcnt lgkmcnt(0)" ::: "memory");

    // ---- PV: O[16q][64d] += P[16][64] * V[64][64], 8 MFMAs ----
    bf8v pa[2];
#pragma unroll
    for (int ks = 0; ks < 2; ++ks)
      pa[ks] = __builtin_bit_cast(
          bf8v, *(const sh8*)&Ps[w][c * 64 + ((8 * g + 32 * ks) ^ ((c & 7) << 3))]);
#pragma unroll
    for (int ks = 0; ks < 2; ++ks)
#pragma unroll
      for (int dsub = 0; dsub < 4; ++dsub) {
        const int row = 16 * dsub + c;
        const bf8v vf = __builtin_bit_cast(
            bf8v, *(const sh8*)&Vts[row * 64 + ((8 * g + 32 * ks) ^ ((row & 7) << 3))]);
        o_acc[dsub] = __builtin_amdgcn_mfma_f32_16x16x32_bf16(pa[ks], vf, o_acc[dsub], 0, 0, 0);
      }
  }

  // ---- epilogue: divide by l, write bf16 scattered ----
  const int b = bh >> 4, h = bh & 15;
  float rl[4];
#pragma unroll
  for (int i = 0; i < 4; ++i) rl[i] = 1.f / l_i[i];
#pragma unroll
  for (int dsub = 0; dsub < 4; ++dsub)
#pragma unroll
    for (int i = 0; i < 4; ++i) {
      const int q = q0w + 4 * g + i;
      const int d = 16 * dsub + c;
      O[((size_t)(b * 2048 + q)) * 1024 + h * 64 + d] = f2bf(o_acc[dsub][i] * rl[i]);
    }
}

extern "C" void kernel_launch(void* const* d_in, const int* in_sizes, int n_in,
                              void* d_out, int out_size, void* d_ws, size_t ws_size,
                              hipStream_t stream) {
  const float* x      = (const float*)d_in[0];
  const float* qkv_w  = (const float*)d_in[1];
  const float* proj_w = (const float*)d_in[2];
  const float* proj_b = (const float*)d_in[3];
  float* out = (float*)d_out;

  unsigned short* ws = (unsigned short*)d_ws;
  const size_t NE = (size_t)8192 * 1024;        // 8,388,608
  unsigned short* xb     = ws;                  // x bf16 [8192][1024]; reused as attn out
  unsigned short* wqkvT  = xb + NE;             // [3072][1024]
  unsigned short* wprojT = wqkvT + (size_t)3072 * 1024;   // [1024][1024]
  unsigned short* qb     = wprojT + (size_t)1024 * 1024;  // [64][2048][64]
  unsigned short* kb     = qb + NE;
  unsigned short* vb     = kb + NE;
  unsigned short* ab     = xb;                  // attn output reuses xb

  cast_kernel<<<8192, 256, 0, stream>>>(x, xb);
  transpose_cast_kernel<<<dim3(96, 32), dim3(32, 8), 0, stream>>>(qkv_w, wqkvT, 1024, 3072);
  transpose_cast_kernel<<<dim3(32, 32), dim3(32, 8), 0, stream>>>(proj_w, wprojT, 1024, 1024);

  gemm_bf16_kernel<0><<<dim3(64, 24), 256, 0, stream>>>(
      xb, wqkvT, 8192, 3072, 1024, qb, kb, vb, nullptr, nullptr);

  attn_kernel<<<dim3(32, 64), 256, 0, stream>>>(qb, kb, vb, ab);

  gemm_bf16_kernel<1><<<dim3(64, 8), 256, 0, stream>>>(
      ab, wprojT, 8192, 1024, 1024, nullptr, nullptr, nullptr, proj_b, out);
}

// Round 3
// 309.733 us; speedup vs baseline: 12.6581x; 1.1507x over previous
//
#include <hip/hip_runtime.h>

typedef __attribute__((ext_vector_type(8))) short sh8;
typedef __attribute__((ext_vector_type(8))) __bf16 bf8v;
typedef __attribute__((ext_vector_type(4))) float f4v;

__device__ __forceinline__ unsigned short f2bf(float f) {
  unsigned u = __builtin_bit_cast(unsigned, f);
  u += 0x7fffu + ((u >> 16) & 1u);
  return (unsigned short)(u >> 16);
}
__device__ __forceinline__ float bf2f(unsigned short h) {
  unsigned u = ((unsigned)h) << 16;
  return __builtin_bit_cast(float, u);
}

// async global->LDS, 16B per lane; LDS dest = wave-uniform base + lane*16
__device__ __forceinline__ void glds16(const unsigned short* g, unsigned short* l) {
  __builtin_amdgcn_global_load_lds((const __attribute__((address_space(1))) void*)g,
                                   (__attribute__((address_space(3))) void*)l, 16, 0, 0);
}

// ---------------- cast x -> bf16 (vectorized) ----------------
__global__ __launch_bounds__(256) void cast_kernel(const float* __restrict__ in,
                                                   unsigned short* __restrict__ out) {
  const int idx = (blockIdx.x * 256 + threadIdx.x) * 4;
  const float4 v = *(const float4*)(in + idx);
  ushort4 o;
  o.x = f2bf(v.x); o.y = f2bf(v.y); o.z = f2bf(v.z); o.w = f2bf(v.w);
  *(ushort4*)(out + idx) = o;
}

// ---------------- transpose + cast weights: in[R][C] -> out[C][R] bf16 ----------------
__global__ __launch_bounds__(256) void transpose_cast_kernel(const float* __restrict__ in,
                                                             unsigned short* __restrict__ out,
                                                             int R, int C) {
  __shared__ float tile[32][33];
  const int c0 = blockIdx.x * 32, r0 = blockIdx.y * 32;
  const int tx = threadIdx.x, ty = threadIdx.y;
#pragma unroll
  for (int i = 0; i < 4; ++i)
    tile[ty + 8 * i][tx] = in[(size_t)(r0 + ty + 8 * i) * C + c0 + tx];
  __syncthreads();
#pragma unroll
  for (int i = 0; i < 4; ++i)
    out[(size_t)(c0 + ty + 8 * i) * R + r0 + tx] = f2bf(tile[tx][ty + 8 * i]);
}

// ---------------- transpose V: v[bh][2048][64] -> vt[bh][64][2048] (bf16) ----------
__global__ __launch_bounds__(256) void transpose_v_kernel(
    const unsigned short* __restrict__ V, unsigned short* __restrict__ Vt) {
  __shared__ alignas(16) unsigned short T[64 * 64];
  const int bh = blockIdx.y;
  const int n0 = blockIdx.x * 64;
  const int tid = threadIdx.x;
  {
    const int r = tid >> 2;          // 0..63 (n within tile)
    const int seg = tid & 3;
#pragma unroll
    for (int s = 0; s < 2; ++s) {
      const int sg = seg + 4 * s;    // 0..7
      const sh8 v = *(const sh8*)&V[((size_t)bh * 2048 + n0 + r) * 64 + sg * 8];
      *(sh8*)&T[r * 64 + ((sg * 8) ^ ((r & 7) << 3))] = v;
    }
  }
  __syncthreads();
  const int d = tid & 63;
  const int h2 = tid >> 6;           // n-quarter
  unsigned buf[8];
#pragma unroll
  for (int t = 0; t < 8; ++t) {
    const int n1 = h2 * 16 + 2 * t;
    const unsigned short a = T[n1 * 64 + (d ^ ((n1 & 7) << 3))];
    const unsigned short b = T[(n1 + 1) * 64 + (d ^ (((n1 + 1) & 7) << 3))];
    buf[t] = (unsigned)a | ((unsigned)b << 16);
  }
  unsigned short* dst = Vt + ((size_t)bh * 64 + d) * 2048 + n0 + h2 * 16;
  *(uint4*)dst = *(uint4*)&buf[0];
  *(uint4*)(dst + 8) = *(uint4*)&buf[4];
}

// ---------------- bf16 MFMA GEMM (m97 structure): C = A[M][K] @ Bt[N][K]^T ----------
template <int MODE>
__global__ __launch_bounds__(256) void gemm_bf16_kernel(
    const unsigned short* __restrict__ A,   // [M][K] bf16
    const unsigned short* __restrict__ Bt,  // [N][K] bf16
    int M, int N, int K,
    unsigned short* __restrict__ q_out, unsigned short* __restrict__ k_out,
    unsigned short* __restrict__ v_out,
    const float* __restrict__ bias, float* __restrict__ c_out) {
  constexpr int BM = 128, BN = 128, BK = 32;
  __shared__ alignas(16) unsigned short As[BM * 32];
  __shared__ alignas(16) unsigned short Bs[BN * 32];
  const int tid = threadIdx.x;
  const int lane = tid & 63;
  const int wave = tid >> 6;
  const int wr = (wave >> 1) * 64;
  const int wc = (wave & 1) * 64;
  const int bm = blockIdx.x * BM;
  const int bn = blockIdx.y * BN;
  const int fr = lane & 15;
  const int kq = lane >> 4;

  f4v acc[4][4] = {};

  const int r16 = lane >> 2;
  const int slot = (lane & 3) ^ (r16 & 3);

  for (int k0 = 0; k0 < K; k0 += BK) {
    __syncthreads();
#pragma unroll
    for (int s = 0; s < 2; ++s) {
      const int rbase = wave * 32 + s * 16;
      glds16(&A[(size_t)(bm + rbase + r16) * K + k0 + slot * 8], &As[rbase * 32]);
      glds16(&Bt[(size_t)(bn + rbase + r16) * K + k0 + slot * 8], &Bs[rbase * 32]);
    }
    __syncthreads();
    bf8v af[4], bfv[4];
#pragma unroll
    for (int m = 0; m < 4; ++m) {
      const int row = wr + m * 16 + fr;
      af[m] = __builtin_bit_cast(bf8v, *(const sh8*)&As[row * 32 + ((kq * 8) ^ ((row & 3) << 3))]);
    }
#pragma unroll
    for (int n = 0; n < 4; ++n) {
      const int row = wc + n * 16 + fr;
      bfv[n] = __builtin_bit_cast(bf8v, *(const sh8*)&Bs[row * 32 + ((kq * 8) ^ ((row & 3) << 3))]);
    }
#pragma unroll
    for (int m = 0; m < 4; ++m)
#pragma unroll
      for (int n = 0; n < 4; ++n)
        acc[m][n] = __builtin_amdgcn_mfma_f32_16x16x32_bf16(af[m], bfv[n], acc[m][n], 0, 0, 0);
  }

#pragma unroll
  for (int m = 0; m < 4; ++m) {
#pragma unroll
    for (int n = 0; n < 4; ++n) {
#pragma unroll
      for (int i = 0; i < 4; ++i) {
        const int r = bm + wr + m * 16 + kq * 4 + i;
        const int c = bn + wc + n * 16 + fr;
        const float val = acc[m][n][i];
        if (MODE == 0) {
          const int b = r >> 11, nidx = r & 2047;
          const int which = c >> 10, rem = c & 1023;
          const int h = rem >> 6, d = rem & 63;
          const size_t off = ((size_t)((b * 16 + h) * 2048 + nidx)) * 64 + d;
          if (which == 0)      q_out[off] = f2bf(val * 0.125f);
          else if (which == 1) k_out[off] = f2bf(val);
          else                 v_out[off] = f2bf(val);
        } else {
          c_out[(size_t)r * N + c] = val + bias[c];
        }
      }
    }
  }
}

// ---------------- causal flash attention, MFMA, double-buffered prefetch ----------
// Q/K: [bh][2048][64] bf16 (Q pre-scaled). Vt: [bh][64][2048]. O: [B*2048][1024] bf16.
// 4 waves x 32 q-rows = 128 q/block. KV tile 64, 2-phase prefetch.
__global__ __launch_bounds__(256) void attn_kernel(
    const unsigned short* __restrict__ Q, const unsigned short* __restrict__ Kg,
    const unsigned short* __restrict__ Vtg, unsigned short* __restrict__ O) {
  __shared__ alignas(16) unsigned short Ks[2][64 * 64];
  __shared__ alignas(16) unsigned short Vts[2][64 * 64];
  __shared__ alignas(16) unsigned short Ps[4][32 * 64];
  const int tid = threadIdx.x;
  const int lane = tid & 63;
  const int w = tid >> 6;
  const int c = lane & 15, g = lane >> 4;
  // XCD-aware bijective swizzle (nwg=1024, 8 XCDs): 8 bh per 128-block chunk
  const int wg = (blockIdx.x & 7) * 128 + (blockIdx.x >> 3);
  const int qt = 15 - (wg & 15);            // long blocks first within chunk
  const int bh = wg >> 4;
  const unsigned short* Qb = Q + (size_t)bh * (2048 * 64);
  const unsigned short* Kb = Kg + (size_t)bh * (2048 * 64);
  const unsigned short* Vtb = Vtg + (size_t)bh * (64 * 2048);
  const int q0w = qt * 128 + w * 32;

  // Q A-fragments in registers: qa[rh][ds], row=c within rh-subtile
  bf8v qa[2][2];
#pragma unroll
  for (int rh = 0; rh < 2; ++rh)
#pragma unroll
    for (int ds = 0; ds < 2; ++ds)
      qa[rh][ds] = __builtin_bit_cast(
          bf8v, *(const sh8*)&Qb[(size_t)(q0w + rh * 16 + c) * 64 + 8 * g + 32 * ds]);

  f4v o_acc[2][4] = {};
  float m_i[2][4], l_i[2][4];
#pragma unroll
  for (int rh = 0; rh < 2; ++rh)
#pragma unroll
    for (int i = 0; i < 4; ++i) { m_i[rh][i] = -1e30f; l_i[rh][i] = 0.f; }

  const int r8 = lane >> 3;
  const int slot = (lane & 7) ^ r8;
  const int rb0 = w * 16, rb1 = w * 16 + 8;

#define STAGE(buf, jj)                                                                   \
  {                                                                                      \
    glds16(&Kb[(size_t)((jj) * 64 + rb0 + r8) * 64 + slot * 8], &Ks[buf][rb0 * 64]);     \
    glds16(&Kb[(size_t)((jj) * 64 + rb1 + r8) * 64 + slot * 8], &Ks[buf][rb1 * 64]);     \
    glds16(&Vtb[(size_t)(rb0 + r8) * 2048 + (jj) * 64 + slot * 8], &Vts[buf][rb0 * 64]); \
    glds16(&Vtb[(size_t)(rb1 + r8) * 2048 + (jj) * 64 + slot * 8], &Vts[buf][rb1 * 64]); \
  }

  const int jmax = 2 * qt + 1;
  STAGE(0, 0);
  __syncthreads();

  for (int j = 0; j <= jmax; ++j) {
    const int cur = j & 1;
    if (j < jmax) STAGE(cur ^ 1, j + 1);

    // ---- QK^T: S[32q][64k] ----
    f4v s[2][4] = {};
#pragma unroll
    for (int ds = 0; ds < 2; ++ds) {
      bf8v kf[4];
#pragma unroll
      for (int sub = 0; sub < 4; ++sub) {
        const int row = 16 * sub + c;
        kf[sub] = __builtin_bit_cast(
            bf8v, *(const sh8*)&Ks[cur][row * 64 + ((8 * g + 32 * ds) ^ ((row & 7) << 3))]);
      }
      __builtin_amdgcn_s_setprio(1);
#pragma unroll
      for (int rh = 0; rh < 2; ++rh)
#pragma unroll
        for (int sub = 0; sub < 4; ++sub)
          s[rh][sub] = __builtin_amdgcn_mfma_f32_16x16x32_bf16(qa[rh][ds], kf[sub], s[rh][sub], 0, 0, 0);
      __builtin_amdgcn_s_setprio(0);
    }

    // ---- causal mask on the last two tiles ----
    if (j >= 2 * qt) {
      const int koff = 64 * (j - 2 * qt);
#pragma unroll
      for (int rh = 0; rh < 2; ++rh)
#pragma unroll
        for (int sub = 0; sub < 4; ++sub)
#pragma unroll
          for (int i = 0; i < 4; ++i)
            if (koff + 16 * sub + c > w * 32 + rh * 16 + 4 * g + i) s[rh][sub][i] = -1e30f;
    }

    // ---- online softmax (row q = 4g+i per rh; col k = c+16sub) ----
    float alpha[2][4];
#pragma unroll
    for (int rh = 0; rh < 2; ++rh)
#pragma unroll
      for (int i = 0; i < 4; ++i) {
        float mx = fmaxf(fmaxf(s[rh][0][i], s[rh][1][i]), fmaxf(s[rh][2][i], s[rh][3][i]));
#pragma unroll
        for (int off = 8; off; off >>= 1) mx = fmaxf(mx, __shfl_xor(mx, off));
        const float mn = fmaxf(m_i[rh][i], mx);
        float sm = 0.f;
#pragma unroll
        for (int sub = 0; sub < 4; ++sub) {
          const float p = __expf(s[rh][sub][i] - mn);
          s[rh][sub][i] = p;
          sm += p;
        }
#pragma unroll
        for (int off = 8; off; off >>= 1) sm += __shfl_xor(sm, off);
        alpha[rh][i] = __expf(m_i[rh][i] - mn);
        l_i[rh][i] = l_i[rh][i] * alpha[rh][i] + sm;
        m_i[rh][i] = mn;
      }
#pragma unroll
    for (int rh = 0; rh < 2; ++rh)
#pragma unroll
      for (int dsub = 0; dsub < 4; ++dsub)
#pragma unroll
        for (int i = 0; i < 4; ++i) o_acc[rh][dsub][i] *= alpha[rh][i];

    // ---- P -> LDS (bf16, swizzled, per-wave) ----
#pragma unroll
    for (int rh = 0; rh < 2; ++rh)
#pragma unroll
      for (int sub = 0; sub < 4; ++sub)
#pragma unroll
        for (int i = 0; i < 4; ++i) {
          const int row = rh * 16 + 4 * g + i;
          Ps[w][row * 64 + ((c + 16 * sub) ^ ((row & 7) << 3))] = f2bf(s[rh][sub][i]);
        }
    asm volatile("s_waitcnt lgkmcnt(0)" ::: "memory");

    // ---- PV: O[32q][64d] += P[32][64] * V[64][64] ----
#pragma unroll
    for (int ks = 0; ks < 2; ++ks) {
      bf8v vf[4];
#pragma unroll
      for (int dsub = 0; dsub < 4; ++dsub) {
        const int row = 16 * dsub + c;
        vf[dsub] = __builtin_bit_cast(
            bf8v, *(const sh8*)&Vts[cur][row * 64 + ((8 * g + 32 * ks) ^ ((row & 7) << 3))]);
      }
      bf8v pa[2];
#pragma unroll
      for (int rh = 0; rh < 2; ++rh)
        pa[rh] = __builtin_bit_cast(
            bf8v, *(const sh8*)&Ps[w][(rh * 16 + c) * 64 + ((8 * g + 32 * ks) ^ ((c & 7) << 3))]);
      __builtin_amdgcn_s_setprio(1);
#pragma unroll
      for (int rh = 0; rh < 2; ++rh)
#pragma unroll
        for (int dsub = 0; dsub < 4; ++dsub)
          o_acc[rh][dsub] = __builtin_amdgcn_mfma_f32_16x16x32_bf16(pa[rh], vf[dsub], o_acc[rh][dsub], 0, 0, 0);
      __builtin_amdgcn_s_setprio(0);
    }
    __syncthreads();
  }
#undef STAGE

  // ---- epilogue ----
  const int b = bh >> 4, h = bh & 15;
#pragma unroll
  for (int rh = 0; rh < 2; ++rh) {
    float rl[4];
#pragma unroll
    for (int i = 0; i < 4; ++i) rl[i] = 1.f / l_i[rh][i];
#pragma unroll
    for (int dsub = 0; dsub < 4; ++dsub)
#pragma unroll
      for (int i = 0; i < 4; ++i) {
        const int q = q0w + rh * 16 + 4 * g + i;
        const int d = 16 * dsub + c;
        O[((size_t)(b * 2048 + q)) * 1024 + h * 64 + d] = f2bf(o_acc[rh][dsub][i] * rl[i]);
      }
  }
}

extern "C" void kernel_launch(void* const* d_in, const int* in_sizes, int n_in,
                              void* d_out, int out_size, void* d_ws, size_t ws_size,
                              hipStream_t stream) {
  const float* x      = (const float*)d_in[0];
  const float* qkv_w  = (const float*)d_in[1];
  const float* proj_w = (const float*)d_in[2];
  const float* proj_b = (const float*)d_in[3];
  float* out = (float*)d_out;

  unsigned short* ws = (unsigned short*)d_ws;
  const size_t NE = (size_t)8192 * 1024;        // 8,388,608
  unsigned short* xb     = ws;                  // x bf16; reused as attn out
  unsigned short* wqkvT  = xb + NE;             // [3072][1024]
  unsigned short* wprojT = wqkvT + (size_t)3072 * 1024;
  unsigned short* qb     = wprojT + (size_t)1024 * 1024;  // [64][2048][64]
  unsigned short* kb     = qb + NE;
  unsigned short* vb     = kb + NE;
  unsigned short* vt     = vb + NE;             // [64][64][2048]
  unsigned short* ab     = xb;

  cast_kernel<<<8192, 256, 0, stream>>>(x, xb);
  transpose_cast_kernel<<<dim3(96, 32), dim3(32, 8), 0, stream>>>(qkv_w, wqkvT, 1024, 3072);
  transpose_cast_kernel<<<dim3(32, 32), dim3(32, 8), 0, stream>>>(proj_w, wprojT, 1024, 1024);

  gemm_bf16_kernel<0><<<dim3(64, 24), 256, 0, stream>>>(
      xb, wqkvT, 8192, 3072, 1024, qb, kb, vb, nullptr, nullptr);

  transpose_v_kernel<<<dim3(32, 64), 256, 0, stream>>>(vb, vt);

  attn_kernel<<<1024, 256, 0, stream>>>(qb, kb, vt, ab);

  gemm_bf16_kernel<1><<<dim3(64, 8), 256, 0, stream>>>(
      ab, wprojT, 8192, 1024, 1024, nullptr, nullptr, nullptr, proj_b, out);
}

// Round 5
// 213.966 us; speedup vs baseline: 18.3236x; 1.4476x over previous
//
#include <hip/hip_runtime.h>

typedef __attribute__((ext_vector_type(8))) short sh8;
typedef __attribute__((ext_vector_type(8))) __bf16 bf8v;
typedef __attribute__((ext_vector_type(4))) float f4v;
typedef __attribute__((ext_vector_type(16))) float f16v;
typedef __attribute__((ext_vector_type(4))) unsigned u4v;

__device__ __forceinline__ float fast_exp2(float x) { return __builtin_amdgcn_exp2f(x); }

__device__ __forceinline__ unsigned short f2bf(float f) {
  unsigned u = __builtin_bit_cast(unsigned, f);
  u += 0x7fffu + ((u >> 16) & 1u);
  return (unsigned short)(u >> 16);
}
__device__ __forceinline__ float bf2f(unsigned short h) {
  unsigned u = ((unsigned)h) << 16;
  return __builtin_bit_cast(float, u);
}

// async global->LDS, 16B per lane; LDS dest = wave-uniform base + lane*16
__device__ __forceinline__ void glds16(const unsigned short* g, unsigned short* l) {
  __builtin_amdgcn_global_load_lds((const __attribute__((address_space(1))) void*)g,
                                   (__attribute__((address_space(3))) void*)l, 16, 0, 0);
}

// ---------------- cast x -> bf16 (vectorized) ----------------
__global__ __launch_bounds__(256) void cast_kernel(const float* __restrict__ in,
                                                   unsigned short* __restrict__ out) {
  const int idx = (blockIdx.x * 256 + threadIdx.x) * 4;
  const float4 v = *(const float4*)(in + idx);
  ushort4 o;
  o.x = f2bf(v.x); o.y = f2bf(v.y); o.z = f2bf(v.z); o.w = f2bf(v.w);
  *(ushort4*)(out + idx) = o;
}

// ---------------- transpose + cast weights: in[R][C] -> out[C][R] bf16 ----------------
__global__ __launch_bounds__(256) void transpose_cast_kernel(const float* __restrict__ in,
                                                             unsigned short* __restrict__ out,
                                                             int R, int C) {
  __shared__ float tile[32][33];
  const int c0 = blockIdx.x * 32, r0 = blockIdx.y * 32;
  const int tx = threadIdx.x, ty = threadIdx.y;
#pragma unroll
  for (int i = 0; i < 4; ++i)
    tile[ty + 8 * i][tx] = in[(size_t)(r0 + ty + 8 * i) * C + c0 + tx];
  __syncthreads();
#pragma unroll
  for (int i = 0; i < 4; ++i)
    out[(size_t)(c0 + ty + 8 * i) * R + r0 + tx] = f2bf(tile[tx][ty + 8 * i]);
}

// ---------------- transpose V: v[bh][2048][64] -> vt[bh][64][2048] (bf16) ----------
__global__ __launch_bounds__(256) void transpose_v_kernel(
    const unsigned short* __restrict__ V, unsigned short* __restrict__ Vt) {
  __shared__ alignas(16) unsigned short T[64 * 64];
  const int bh = blockIdx.y;
  const int n0 = blockIdx.x * 64;
  const int tid = threadIdx.x;
  {
    const int r = tid >> 2;
    const int seg = tid & 3;
#pragma unroll
    for (int s = 0; s < 2; ++s) {
      const int sg = seg + 4 * s;
      const sh8 v = *(const sh8*)&V[((size_t)bh * 2048 + n0 + r) * 64 + sg * 8];
      *(sh8*)&T[r * 64 + ((sg * 8) ^ ((r & 7) << 3))] = v;
    }
  }
  __syncthreads();
  const int d = tid & 63;
  const int h2 = tid >> 6;
  unsigned buf[8];
#pragma unroll
  for (int t = 0; t < 8; ++t) {
    const int n1 = h2 * 16 + 2 * t;
    const unsigned short a = T[n1 * 64 + (d ^ ((n1 & 7) << 3))];
    const unsigned short b = T[(n1 + 1) * 64 + (d ^ (((n1 + 1) & 7) << 3))];
    buf[t] = (unsigned)a | ((unsigned)b << 16);
  }
  unsigned short* dst = Vt + ((size_t)bh * 64 + d) * 2048 + n0 + h2 * 16;
  *(uint4*)dst = *(uint4*)&buf[0];
  *(uint4*)(dst + 8) = *(uint4*)&buf[4];
}

// ---------------- bf16 MFMA GEMM (m97 structure): C = A[M][K] @ Bt[N][K]^T ----------
// MODE 0: QKV epilogue -> q/k/v [B*H][N][64] bf16; Q scaled by 0.125*log2(e) (exp2-domain softmax)
// MODE 1: proj epilogue -> out = acc + bias (fp32)
template <int MODE>
__global__ __launch_bounds__(256) void gemm_bf16_kernel(
    const unsigned short* __restrict__ A,
    const unsigned short* __restrict__ Bt,
    int M, int N, int K,
    unsigned short* __restrict__ q_out, unsigned short* __restrict__ k_out,
    unsigned short* __restrict__ v_out,
    const float* __restrict__ bias, float* __restrict__ c_out) {
  constexpr int BM = 128, BN = 128, BK = 32;
  __shared__ alignas(16) unsigned short As[BM * 32];
  __shared__ alignas(16) unsigned short Bs[BN * 32];
  const int tid = threadIdx.x;
  const int lane = tid & 63;
  const int wave = tid >> 6;
  const int wr = (wave >> 1) * 64;
  const int wc = (wave & 1) * 64;
  const int bm = blockIdx.x * BM;
  const int bn = blockIdx.y * BN;
  const int fr = lane & 15;
  const int kq = lane >> 4;

  f4v acc[4][4] = {};

  const int r16 = lane >> 2;
  const int slot = (lane & 3) ^ (r16 & 3);

  for (int k0 = 0; k0 < K; k0 += BK) {
    __syncthreads();
#pragma unroll
    for (int s = 0; s < 2; ++s) {
      const int rbase = wave * 32 + s * 16;
      glds16(&A[(size_t)(bm + rbase + r16) * K + k0 + slot * 8], &As[rbase * 32]);
      glds16(&Bt[(size_t)(bn + rbase + r16) * K + k0 + slot * 8], &Bs[rbase * 32]);
    }
    __syncthreads();
    bf8v af[4], bfv[4];
#pragma unroll
    for (int m = 0; m < 4; ++m) {
      const int row = wr + m * 16 + fr;
      af[m] = __builtin_bit_cast(bf8v, *(const sh8*)&As[row * 32 + ((kq * 8) ^ ((row & 3) << 3))]);
    }
#pragma unroll
    for (int n = 0; n < 4; ++n) {
      const int row = wc + n * 16 + fr;
      bfv[n] = __builtin_bit_cast(bf8v, *(const sh8*)&Bs[row * 32 + ((kq * 8) ^ ((row & 3) << 3))]);
    }
#pragma unroll
    for (int m = 0; m < 4; ++m)
#pragma unroll
      for (int n = 0; n < 4; ++n)
        acc[m][n] = __builtin_amdgcn_mfma_f32_16x16x32_bf16(af[m], bfv[n], acc[m][n], 0, 0, 0);
  }

#pragma unroll
  for (int m = 0; m < 4; ++m) {
#pragma unroll
    for (int n = 0; n < 4; ++n) {
#pragma unroll
      for (int i = 0; i < 4; ++i) {
        const int r = bm + wr + m * 16 + kq * 4 + i;
        const int c = bn + wc + n * 16 + fr;
        const float val = acc[m][n][i];
        if (MODE == 0) {
          const int b = r >> 11, nidx = r & 2047;
          const int which = c >> 10, rem = c & 1023;
          const int h = rem >> 6, d = rem & 63;
          const size_t off = ((size_t)((b * 16 + h) * 2048 + nidx)) * 64 + d;
          if (which == 0)      q_out[off] = f2bf(val * 0.18033688f);  // 0.125 * log2(e)
          else if (which == 1) k_out[off] = f2bf(val);
          else                 v_out[off] = f2bf(val);
        } else {
          c_out[(size_t)r * N + c] = val + bias[c];
        }
      }
    }
  }
}

// ---------------- causal flash attention: swapped QK^T (32x32x16), in-register softmax ----
// Q/K: [bh][2048][64] bf16 (Q pre-scaled by 0.125*log2e). Vt: [bh][64][2048]. O: [B*2048][1024].
// 4 waves x 32 q-rows = 128 q/block; KV tile 64; double-buffered LDS prefetch.
// S^T = mfma(K, Q): lane owns q = q0w + (lane&31); k-rows = crow(r,hi)=(r&3)+8(r>>2)+4hi (+32*kb).
__global__ __launch_bounds__(256, 3) void attn_kernel(
    const unsigned short* __restrict__ Q, const unsigned short* __restrict__ Kg,
    const unsigned short* __restrict__ Vtg, unsigned short* __restrict__ O) {
  __shared__ alignas(16) unsigned short Ks[2][64 * 64];
  __shared__ alignas(16) unsigned short Vts[2][64 * 64];
  const int tid = threadIdx.x;
  const int lane = tid & 63;
  const int w = tid >> 6;
  const int q31 = lane & 31, hi = lane >> 5;
  const int sw = (lane & 7) << 3;           // read swizzle (row&7)==lane&7 for our rows
  // XCD-aware bijective swizzle (nwg=1024): 8 bh per 128-block chunk, long-first
  const int wg = (blockIdx.x & 7) * 128 + (blockIdx.x >> 3);
  const int qt = 15 - (wg & 15);
  const int bh = wg >> 4;
  const unsigned short* Qb = Q + (size_t)bh * (2048 * 64);
  const unsigned short* Kb = Kg + (size_t)bh * (2048 * 64);
  const unsigned short* Vtb = Vtg + (size_t)bh * (64 * 2048);
  const int q0w = qt * 128 + w * 32;
  const int qg = q0w + q31;                 // this lane's q

  // Q B-fragments in registers: lane holds Q[qg][8hi + 16dk + t]
  bf8v qf[4];
#pragma unroll
  for (int dk = 0; dk < 4; ++dk)
    qf[dk] = __builtin_bit_cast(bf8v, *(const sh8*)&Qb[(size_t)qg * 64 + 8 * hi + 16 * dk]);

  f16v o0 = {}, o1 = {};                    // O cols d = q31 (+32)
  float m_i = -1e30f, l_i = 0.f;

  const int r8 = lane >> 3;
  const int gslot = (lane & 7) ^ r8;
  const int rb0 = w * 16, rb1 = w * 16 + 8;

#define STAGE(buf, jj)                                                                     \
  {                                                                                        \
    glds16(&Kb[(size_t)((jj) * 64 + rb0 + r8) * 64 + gslot * 8], &Ks[buf][rb0 * 64]);      \
    glds16(&Kb[(size_t)((jj) * 64 + rb1 + r8) * 64 + gslot * 8], &Ks[buf][rb1 * 64]);      \
    glds16(&Vtb[(size_t)(rb0 + r8) * 2048 + (jj) * 64 + gslot * 8], &Vts[buf][rb0 * 64]);  \
    glds16(&Vtb[(size_t)(rb1 + r8) * 2048 + (jj) * 64 + gslot * 8], &Vts[buf][rb1 * 64]);  \
  }

  const int jmax = 2 * qt + 1;
  STAGE(0, 0);
  __syncthreads();

  for (int j = 0; j <= jmax; ++j) {
    const int cur = j & 1;
    if (j < jmax) STAGE(cur ^ 1, j + 1);

    // ---- QK^T (swapped): S^T[k][q], 8 MFMAs ----
    f16v s0 = {}, s1 = {};
    __builtin_amdgcn_s_setprio(1);
#pragma unroll
    for (int dk = 0; dk < 4; ++dk) {
      const int col = (8 * hi + 16 * dk) ^ sw;
      const bf8v k0 = __builtin_bit_cast(bf8v, *(const sh8*)&Ks[cur][q31 * 64 + col]);
      const bf8v k1 = __builtin_bit_cast(bf8v, *(const sh8*)&Ks[cur][(32 + q31) * 64 + col]);
      s0 = __builtin_amdgcn_mfma_f32_32x32x16_bf16(k0, qf[dk], s0, 0, 0, 0);
      s1 = __builtin_amdgcn_mfma_f32_32x32x16_bf16(k1, qf[dk], s1, 0, 0, 0);
    }
    __builtin_amdgcn_s_setprio(0);

    // ---- causal mask (diagonal region only) ----
    if (j * 64 + 63 > q0w) {
#pragma unroll
      for (int r = 0; r < 16; ++r) {
        const int kl = j * 64 + (r & 3) + 8 * (r >> 2) + 4 * hi;
        if (kl > qg) s0[r] = -1e30f;
        if (kl + 32 > qg) s1[r] = -1e30f;
      }
    }

    // ---- in-register row max (31 fmax + 1 cross-half shfl) ----
    float mx = -1e30f;
#pragma unroll
    for (int r = 0; r < 16; ++r) mx = fmaxf(mx, fmaxf(s0[r], s1[r]));
    mx = fmaxf(mx, __shfl_xor(mx, 32));

    // ---- defer-max rescale (rare path) ----
    if (!__all(mx - m_i <= 8.f)) {
      const float mn = fmaxf(m_i, mx);
      const float alpha = fast_exp2(m_i - mn);
      m_i = mn;
      l_i *= alpha;
#pragma unroll
      for (int r = 0; r < 16; ++r) {
        const float ar = __shfl(alpha, (r & 3) + 8 * (r >> 2) + 4 * hi);
        o0[r] *= ar;
        o1[r] *= ar;
      }
    }

    // ---- P = exp2(S - m), row sum in-register ----
    float ps = 0.f;
#pragma unroll
    for (int r = 0; r < 16; ++r) {
      s0[r] = fast_exp2(s0[r] - m_i);
      s1[r] = fast_exp2(s1[r] - m_i);
      ps += s0[r] + s1[r];
    }
    ps += __shfl_xor(ps, 32);
    l_i += ps;

    // ---- pack P to bf16 pairs (k ascending) ----
    unsigned w0[8], w1[8];
#pragma unroll
    for (int jj = 0; jj < 8; ++jj) {
      asm("v_cvt_pk_bf16_f32 %0, %1, %2" : "=v"(w0[jj]) : "v"(s0[2 * jj]), "v"(s0[2 * jj + 1]));
      asm("v_cvt_pk_bf16_f32 %0, %1, %2" : "=v"(w1[jj]) : "v"(s1[2 * jj]), "v"(s1[2 * jj + 1]));
    }

    // ---- redistribute to PV A-frags via permlane32_swap, then PV MFMAs ----
#pragma unroll
    for (int ks = 0; ks < 4; ++ks) {
      const int j0 = 4 * (ks & 1);
      unsigned x0 = (ks < 2 ? w0[j0 + 0] : w1[j0 + 0]);
      unsigned y0 = (ks < 2 ? w0[j0 + 2] : w1[j0 + 2]);
      unsigned x1 = (ks < 2 ? w0[j0 + 1] : w1[j0 + 1]);
      unsigned y1 = (ks < 2 ? w0[j0 + 3] : w1[j0 + 3]);
      asm("v_permlane32_swap_b32 %0, %1" : "+v"(x0), "+v"(y0));
      asm("v_permlane32_swap_b32 %0, %1" : "+v"(x1), "+v"(y1));
      u4v pw;
      pw[0] = x0; pw[1] = x1; pw[2] = y0; pw[3] = y1;
      const bf8v pa = __builtin_bit_cast(bf8v, pw);

      const int colv = (8 * hi + 16 * ks) ^ sw;
      const bf8v vf0 = __builtin_bit_cast(bf8v, *(const sh8*)&Vts[cur][q31 * 64 + colv]);
      const bf8v vf1 = __builtin_bit_cast(bf8v, *(const sh8*)&Vts[cur][(32 + q31) * 64 + colv]);
      __builtin_amdgcn_s_setprio(1);
      o0 = __builtin_amdgcn_mfma_f32_32x32x16_bf16(pa, vf0, o0, 0, 0, 0);
      o1 = __builtin_amdgcn_mfma_f32_32x32x16_bf16(pa, vf1, o1, 0, 0, 0);
      __builtin_amdgcn_s_setprio(0);
    }
    __syncthreads();
  }
#undef STAGE

  // ---- epilogue: O rows q = q0w + crow(r,hi), cols d = q31 (+32) ----
  const int b = bh >> 4, h = bh & 15;
  const float rl = 1.f / l_i;
#pragma unroll
  for (int r = 0; r < 16; ++r) {
    const int cr = (r & 3) + 8 * (r >> 2) + 4 * hi;
    const float lr = __shfl(rl, cr);
    const size_t base = ((size_t)(b * 2048 + q0w + cr)) * 1024 + h * 64 + q31;
    O[base] = f2bf(o0[r] * lr);
    O[base + 32] = f2bf(o1[r] * lr);
  }
}

extern "C" void kernel_launch(void* const* d_in, const int* in_sizes, int n_in,
                              void* d_out, int out_size, void* d_ws, size_t ws_size,
                              hipStream_t stream) {
  const float* x      = (const float*)d_in[0];
  const float* qkv_w  = (const float*)d_in[1];
  const float* proj_w = (const float*)d_in[2];
  const float* proj_b = (const float*)d_in[3];
  float* out = (float*)d_out;

  unsigned short* ws = (unsigned short*)d_ws;
  const size_t NE = (size_t)8192 * 1024;
  unsigned short* xb     = ws;
  unsigned short* wqkvT  = xb + NE;
  unsigned short* wprojT = wqkvT + (size_t)3072 * 1024;
  unsigned short* qb     = wprojT + (size_t)1024 * 1024;
  unsigned short* kb     = qb + NE;
  unsigned short* vb     = kb + NE;
  unsigned short* vt     = vb + NE;
  unsigned short* ab     = xb;

  cast_kernel<<<8192, 256, 0, stream>>>(x, xb);
  transpose_cast_kernel<<<dim3(96, 32), dim3(32, 8), 0, stream>>>(qkv_w, wqkvT, 1024, 3072);
  transpose_cast_kernel<<<dim3(32, 32), dim3(32, 8), 0, stream>>>(proj_w, wprojT, 1024, 1024);

  gemm_bf16_kernel<0><<<dim3(64, 24), 256, 0, stream>>>(
      xb, wqkvT, 8192, 3072, 1024, qb, kb, vb, nullptr, nullptr);

  transpose_v_kernel<<<dim3(32, 64), 256, 0, stream>>>(vb, vt);

  attn_kernel<<<1024, 256, 0, stream>>>(qb, kb, vt, ab);

  gemm_bf16_kernel<1><<<dim3(64, 8), 256, 0, stream>>>(
      ab, wprojT, 8192, 1024, 1024, nullptr, nullptr, nullptr, proj_b, out);
}

// Round 6
// 194.078 us; speedup vs baseline: 20.2013x; 1.1025x over previous
//
#include <hip/hip_runtime.h>

typedef __attribute__((ext_vector_type(8))) short sh8;
typedef __attribute__((ext_vector_type(8))) __bf16 bf8v;
typedef __attribute__((ext_vector_type(4))) float f4v;
typedef __attribute__((ext_vector_type(16))) float f16v;
typedef __attribute__((ext_vector_type(4))) unsigned u4v;

__device__ __forceinline__ float fast_exp2(float x) { return __builtin_amdgcn_exp2f(x); }

__device__ __forceinline__ unsigned short f2bf(float f) {
  unsigned u = __builtin_bit_cast(unsigned, f);
  u += 0x7fffu + ((u >> 16) & 1u);
  return (unsigned short)(u >> 16);
}
__device__ __forceinline__ float bf2f(unsigned short h) {
  unsigned u = ((unsigned)h) << 16;
  return __builtin_bit_cast(float, u);
}

// async global->LDS, 16B per lane; LDS dest = wave-uniform base + lane*16
__device__ __forceinline__ void glds16(const unsigned short* g, unsigned short* l) {
  __builtin_amdgcn_global_load_lds((const __attribute__((address_space(1))) void*)g,
                                   (__attribute__((address_space(3))) void*)l, 16, 0, 0);
}

// ---------------- cast x -> bf16 (vectorized) ----------------
__global__ __launch_bounds__(256) void cast_kernel(const float* __restrict__ in,
                                                   unsigned short* __restrict__ out) {
  const int idx = (blockIdx.x * 256 + threadIdx.x) * 4;
  const float4 v = *(const float4*)(in + idx);
  ushort4 o;
  o.x = f2bf(v.x); o.y = f2bf(v.y); o.z = f2bf(v.z); o.w = f2bf(v.w);
  *(ushort4*)(out + idx) = o;
}

// ---------------- transpose + cast weights: in[R][C] -> out[C][R] bf16 ----------------
__global__ __launch_bounds__(256) void transpose_cast_kernel(const float* __restrict__ in,
                                                             unsigned short* __restrict__ out,
                                                             int R, int C) {
  __shared__ float tile[32][33];
  const int c0 = blockIdx.x * 32, r0 = blockIdx.y * 32;
  const int tx = threadIdx.x, ty = threadIdx.y;
#pragma unroll
  for (int i = 0; i < 4; ++i)
    tile[ty + 8 * i][tx] = in[(size_t)(r0 + ty + 8 * i) * C + c0 + tx];
  __syncthreads();
#pragma unroll
  for (int i = 0; i < 4; ++i)
    out[(size_t)(c0 + ty + 8 * i) * R + r0 + tx] = f2bf(tile[tx][ty + 8 * i]);
}

// ---------------- transpose V: v[bh][2048][64] -> vt[bh][64][2048] (bf16) ----------
__global__ __launch_bounds__(256) void transpose_v_kernel(
    const unsigned short* __restrict__ V, unsigned short* __restrict__ Vt) {
  __shared__ alignas(16) unsigned short T[64 * 64];
  const int bh = blockIdx.y;
  const int n0 = blockIdx.x * 64;
  const int tid = threadIdx.x;
  {
    const int r = tid >> 2;
    const int seg = tid & 3;
#pragma unroll
    for (int s = 0; s < 2; ++s) {
      const int sg = seg + 4 * s;
      const sh8 v = *(const sh8*)&V[((size_t)bh * 2048 + n0 + r) * 64 + sg * 8];
      *(sh8*)&T[r * 64 + ((sg * 8) ^ ((r & 7) << 3))] = v;
    }
  }
  __syncthreads();
  const int d = tid & 63;
  const int h2 = tid >> 6;
  unsigned buf[8];
#pragma unroll
  for (int t = 0; t < 8; ++t) {
    const int n1 = h2 * 16 + 2 * t;
    const unsigned short a = T[n1 * 64 + (d ^ ((n1 & 7) << 3))];
    const unsigned short b = T[(n1 + 1) * 64 + (d ^ (((n1 + 1) & 7) << 3))];
    buf[t] = (unsigned)a | ((unsigned)b << 16);
  }
  unsigned short* dst = Vt + ((size_t)bh * 64 + d) * 2048 + n0 + h2 * 16;
  *(uint4*)dst = *(uint4*)&buf[0];
  *(uint4*)(dst + 8) = *(uint4*)&buf[4];
}

// ---------------- bf16 MFMA GEMM (m97 structure): C = A[M][K] @ Bt[N][K]^T ----------
// MODE 0: QKV epilogue -> q/k/v [B*H][N][64] bf16; Q scaled by 0.125*log2(e)
// MODE 1: proj epilogue -> out = acc + bias (fp32)
template <int MODE>
__global__ __launch_bounds__(256) void gemm_bf16_kernel(
    const unsigned short* __restrict__ A,
    const unsigned short* __restrict__ Bt,
    int M, int N, int K,
    unsigned short* __restrict__ q_out, unsigned short* __restrict__ k_out,
    unsigned short* __restrict__ v_out,
    const float* __restrict__ bias, float* __restrict__ c_out) {
  constexpr int BM = 128, BN = 128, BK = 32;
  __shared__ alignas(16) unsigned short As[BM * 32];
  __shared__ alignas(16) unsigned short Bs[BN * 32];
  const int tid = threadIdx.x;
  const int lane = tid & 63;
  const int wave = tid >> 6;
  const int wr = (wave >> 1) * 64;
  const int wc = (wave & 1) * 64;
  const int bm = blockIdx.x * BM;
  const int bn = blockIdx.y * BN;
  const int fr = lane & 15;
  const int kq = lane >> 4;

  f4v acc[4][4] = {};

  const int r16 = lane >> 2;
  const int slot = (lane & 3) ^ (r16 & 3);

  for (int k0 = 0; k0 < K; k0 += BK) {
    __syncthreads();
#pragma unroll
    for (int s = 0; s < 2; ++s) {
      const int rbase = wave * 32 + s * 16;
      glds16(&A[(size_t)(bm + rbase + r16) * K + k0 + slot * 8], &As[rbase * 32]);
      glds16(&Bt[(size_t)(bn + rbase + r16) * K + k0 + slot * 8], &Bs[rbase * 32]);
    }
    __syncthreads();
    bf8v af[4], bfv[4];
#pragma unroll
    for (int m = 0; m < 4; ++m) {
      const int row = wr + m * 16 + fr;
      af[m] = __builtin_bit_cast(bf8v, *(const sh8*)&As[row * 32 + ((kq * 8) ^ ((row & 3) << 3))]);
    }
#pragma unroll
    for (int n = 0; n < 4; ++n) {
      const int row = wc + n * 16 + fr;
      bfv[n] = __builtin_bit_cast(bf8v, *(const sh8*)&Bs[row * 32 + ((kq * 8) ^ ((row & 3) << 3))]);
    }
#pragma unroll
    for (int m = 0; m < 4; ++m)
#pragma unroll
      for (int n = 0; n < 4; ++n)
        acc[m][n] = __builtin_amdgcn_mfma_f32_16x16x32_bf16(af[m], bfv[n], acc[m][n], 0, 0, 0);
  }

#pragma unroll
  for (int m = 0; m < 4; ++m) {
#pragma unroll
    for (int n = 0; n < 4; ++n) {
#pragma unroll
      for (int i = 0; i < 4; ++i) {
        const int r = bm + wr + m * 16 + kq * 4 + i;
        const int c = bn + wc + n * 16 + fr;
        const float val = acc[m][n][i];
        if (MODE == 0) {
          const int b = r >> 11, nidx = r & 2047;
          const int which = c >> 10, rem = c & 1023;
          const int h = rem >> 6, d = rem & 63;
          const size_t off = ((size_t)((b * 16 + h) * 2048 + nidx)) * 64 + d;
          if (which == 0)      q_out[off] = f2bf(val * 0.18033688f);  // 0.125 * log2(e)
          else if (which == 1) k_out[off] = f2bf(val);
          else                 v_out[off] = f2bf(val);
        } else {
          c_out[(size_t)r * N + c] = val + bias[c];
        }
      }
    }
  }
}

// ---------------- causal flash attention: swapped QK^T, paired q-tiles, counted vmcnt ----
// Q/K: [bh][2048][64] bf16 (Q pre-scaled by 0.125*log2e). Vt: [bh][64][2048]. O: [B*2048][1024].
// 512 blocks; block = (bh, pair): q-tiles qtA=pair, qtB=15-pair sharing one KV stream.
// 4 waves x 32 q-rows per q-tile. 4-deep LDS buffers, prefetch depth 2, vmcnt(8), raw barrier.
__global__ __launch_bounds__(256, 2) void attn_kernel(
    const unsigned short* __restrict__ Q, const unsigned short* __restrict__ Kg,
    const unsigned short* __restrict__ Vtg, unsigned short* __restrict__ O) {
  __shared__ alignas(16) unsigned short Ks[4][64 * 64];
  __shared__ alignas(16) unsigned short Vts[4][64 * 64];
  const int tid = threadIdx.x;
  const int lane = tid & 63;
  const int w = tid >> 6;
  const int q31 = lane & 31, hi = lane >> 5;
  const int sw = (lane & 7) << 3;
  // XCD-aware bijective swizzle (nwg=512): 8 bh per 64-block chunk
  const int wg = (blockIdx.x & 7) * 64 + (blockIdx.x >> 3);
  const int bh = wg >> 3;
  const int pair = wg & 7;
  const int qtA = pair, qtB = 15 - pair;
  const unsigned short* Qb = Q + (size_t)bh * (2048 * 64);
  const unsigned short* Kb = Kg + (size_t)bh * (2048 * 64);
  const unsigned short* Vtb = Vtg + (size_t)bh * (64 * 2048);
  const int q0wA = qtA * 128 + w * 32;
  const int q0wB = qtB * 128 + w * 32;

  // Q B-fragments for both q-tiles: lane holds Q[q0w+q31][8hi + 16dk + t]
  bf8v qfA[4], qfB[4];
#pragma unroll
  for (int dk = 0; dk < 4; ++dk) {
    qfA[dk] = __builtin_bit_cast(bf8v, *(const sh8*)&Qb[(size_t)(q0wA + q31) * 64 + 8 * hi + 16 * dk]);
    qfB[dk] = __builtin_bit_cast(bf8v, *(const sh8*)&Qb[(size_t)(q0wB + q31) * 64 + 8 * hi + 16 * dk]);
  }

  f16v oA0 = {}, oA1 = {}, oB0 = {}, oB1 = {};
  float mA = -1e30f, lA = 0.f, mB = -1e30f, lB = 0.f;

  const int r8 = lane >> 3;
  const int gslot = (lane & 7) ^ r8;
  const int rb0 = w * 16, rb1 = w * 16 + 8;

#define STAGE(g)                                                                              \
  {                                                                                           \
    const int _b = (g) & 3;                                                                   \
    glds16(&Kb[(size_t)((g) * 64 + rb0 + r8) * 64 + gslot * 8], &Ks[_b][rb0 * 64]);           \
    glds16(&Kb[(size_t)((g) * 64 + rb1 + r8) * 64 + gslot * 8], &Ks[_b][rb1 * 64]);           \
    glds16(&Vtb[(size_t)(rb0 + r8) * 2048 + (g) * 64 + gslot * 8], &Vts[_b][rb0 * 64]);       \
    glds16(&Vtb[(size_t)(rb1 + r8) * 2048 + (g) * 64 + gslot * 8], &Vts[_b][rb1 * 64]);       \
  }

  // one KV-tile body for one q-tile (all state by reference -> static regs)
  auto body = [&](int j, int buf, int q0w, bf8v (&qf)[4], f16v& o0, f16v& o1,
                  float& m_i, float& l_i) {
    f16v s0 = {}, s1 = {};
    __builtin_amdgcn_s_setprio(1);
#pragma unroll
    for (int dk = 0; dk < 4; ++dk) {
      const int col = (8 * hi + 16 * dk) ^ sw;
      const bf8v k0 = __builtin_bit_cast(bf8v, *(const sh8*)&Ks[buf][q31 * 64 + col]);
      const bf8v k1 = __builtin_bit_cast(bf8v, *(const sh8*)&Ks[buf][(32 + q31) * 64 + col]);
      s0 = __builtin_amdgcn_mfma_f32_32x32x16_bf16(k0, qf[dk], s0, 0, 0, 0);
      s1 = __builtin_amdgcn_mfma_f32_32x32x16_bf16(k1, qf[dk], s1, 0, 0, 0);
    }
    __builtin_amdgcn_s_setprio(0);

    const int qg = q0w + q31;
    if (j * 64 + 63 > q0w) {   // diagonal region
#pragma unroll
      for (int r = 0; r < 16; ++r) {
        const int kl = j * 64 + (r & 3) + 8 * (r >> 2) + 4 * hi;
        if (kl > qg) s0[r] = -1e30f;
        if (kl + 32 > qg) s1[r] = -1e30f;
      }
    }

    float mx = -1e30f;
#pragma unroll
    for (int r = 0; r < 16; ++r) mx = fmaxf(mx, fmaxf(s0[r], s1[r]));
    mx = fmaxf(mx, __shfl_xor(mx, 32));

    if (!__all(mx - m_i <= 8.f)) {   // defer-max rare path
      const float mn = fmaxf(m_i, mx);
      const float alpha = fast_exp2(m_i - mn);
      m_i = mn;
      l_i *= alpha;
#pragma unroll
      for (int r = 0; r < 16; ++r) {
        const float ar = __shfl(alpha, (r & 3) + 8 * (r >> 2) + 4 * hi);
        o0[r] *= ar;
        o1[r] *= ar;
      }
    }

    float ps = 0.f;
#pragma unroll
    for (int r = 0; r < 16; ++r) {
      s0[r] = fast_exp2(s0[r] - m_i);
      s1[r] = fast_exp2(s1[r] - m_i);
      ps += s0[r] + s1[r];
    }
    ps += __shfl_xor(ps, 32);
    l_i += ps;

    unsigned w0[8], w1[8];
#pragma unroll
    for (int jj = 0; jj < 8; ++jj) {
      asm("v_cvt_pk_bf16_f32 %0, %1, %2" : "=v"(w0[jj]) : "v"(s0[2 * jj]), "v"(s0[2 * jj + 1]));
      asm("v_cvt_pk_bf16_f32 %0, %1, %2" : "=v"(w1[jj]) : "v"(s1[2 * jj]), "v"(s1[2 * jj + 1]));
    }

#pragma unroll
    for (int ks = 0; ks < 4; ++ks) {
      const int j0 = 4 * (ks & 1);
      unsigned x0 = (ks < 2 ? w0[j0 + 0] : w1[j0 + 0]);
      unsigned y0 = (ks < 2 ? w0[j0 + 2] : w1[j0 + 2]);
      unsigned x1 = (ks < 2 ? w0[j0 + 1] : w1[j0 + 1]);
      unsigned y1 = (ks < 2 ? w0[j0 + 3] : w1[j0 + 3]);
      asm("v_permlane32_swap_b32 %0, %1" : "+v"(x0), "+v"(y0));
      asm("v_permlane32_swap_b32 %0, %1" : "+v"(x1), "+v"(y1));
      u4v pw;
      pw[0] = x0; pw[1] = x1; pw[2] = y0; pw[3] = y1;
      const bf8v pa = __builtin_bit_cast(bf8v, pw);

      const int colv = (8 * hi + 16 * ks) ^ sw;
      const bf8v vf0 = __builtin_bit_cast(bf8v, *(const sh8*)&Vts[buf][q31 * 64 + colv]);
      const bf8v vf1 = __builtin_bit_cast(bf8v, *(const sh8*)&Vts[buf][(32 + q31) * 64 + colv]);
      __builtin_amdgcn_s_setprio(1);
      o0 = __builtin_amdgcn_mfma_f32_32x32x16_bf16(pa, vf0, o0, 0, 0, 0);
      o1 = __builtin_amdgcn_mfma_f32_32x32x16_bf16(pa, vf1, o1, 0, 0, 0);
      __builtin_amdgcn_s_setprio(0);
    }
  };

  const int b = bh >> 4, h = bh & 15;
  auto epi = [&](int q0w, f16v& o0, f16v& o1, float l_i) {
    const float rl = 1.f / l_i;
#pragma unroll
    for (int r = 0; r < 16; ++r) {
      const int cr = (r & 3) + 8 * (r >> 2) + 4 * hi;
      const float lr = __shfl(rl, cr);
      const size_t base = ((size_t)(b * 2048 + q0w + cr)) * 1024 + h * 64 + q31;
      O[base] = f2bf(o0[r] * lr);
      O[base + 32] = f2bf(o1[r] * lr);
    }
  };

  const int nA = 2 * qtA + 2;        // bodyA tiles
  const int nT = 2 * qtB + 2;        // total KV tiles (B is longer; nT > nA always)

  STAGE(0);
  STAGE(1);

  for (int j = 0; j < nT; ++j) {
    const int buf = j & 3;
    if (j + 2 < nT) {
      STAGE(j + 2);
      asm volatile("s_waitcnt vmcnt(8)" ::: "memory");
    } else if (j + 1 < nT) {
      asm volatile("s_waitcnt vmcnt(4)" ::: "memory");
    } else {
      asm volatile("s_waitcnt vmcnt(0)" ::: "memory");
    }
    __builtin_amdgcn_s_barrier();

    if (j < nA) body(j, buf, q0wA, qfA, oA0, oA1, mA, lA);
    body(j, buf, q0wB, qfB, oB0, oB1, mB, lB);

    if (j == nA - 1) epi(q0wA, oA0, oA1, lA);
  }
#undef STAGE

  epi(q0wB, oB0, oB1, lB);
}

extern "C" void kernel_launch(void* const* d_in, const int* in_sizes, int n_in,
                              void* d_out, int out_size, void* d_ws, size_t ws_size,
                              hipStream_t stream) {
  const float* x      = (const float*)d_in[0];
  const float* qkv_w  = (const float*)d_in[1];
  const float* proj_w = (const float*)d_in[2];
  const float* proj_b = (const float*)d_in[3];
  float* out = (float*)d_out;

  unsigned short* ws = (unsigned short*)d_ws;
  const size_t NE = (size_t)8192 * 1024;
  unsigned short* xb     = ws;
  unsigned short* wqkvT  = xb + NE;
  unsigned short* wprojT = wqkvT + (size_t)3072 * 1024;
  unsigned short* qb     = wprojT + (size_t)1024 * 1024;
  unsigned short* kb     = qb + NE;
  unsigned short* vb     = kb + NE;
  unsigned short* vt     = vb + NE;
  unsigned short* ab     = xb;

  cast_kernel<<<8192, 256, 0, stream>>>(x, xb);
  transpose_cast_kernel<<<dim3(96, 32), dim3(32, 8), 0, stream>>>(qkv_w, wqkvT, 1024, 3072);
  transpose_cast_kernel<<<dim3(32, 32), dim3(32, 8), 0, stream>>>(proj_w, wprojT, 1024, 1024);

  gemm_bf16_kernel<0><<<dim3(64, 24), 256, 0, stream>>>(
      xb, wqkvT, 8192, 3072, 1024, qb, kb, vb, nullptr, nullptr);

  transpose_v_kernel<<<dim3(32, 64), 256, 0, stream>>>(vb, vt);

  attn_kernel<<<512, 256, 0, stream>>>(qb, kb, vt, ab);

  gemm_bf16_kernel<1><<<dim3(64, 8), 256, 0, stream>>>(
      ab, wprojT, 8192, 1024, 1024, nullptr, nullptr, nullptr, proj_b, out);
}

// Round 7
// 184.189 us; speedup vs baseline: 21.2859x; 1.0537x over previous
//
#include <hip/hip_runtime.h>

typedef __attribute__((ext_vector_type(8))) short sh8;
typedef __attribute__((ext_vector_type(8))) __bf16 bf8v;
typedef __attribute__((ext_vector_type(4))) float f4v;
typedef __attribute__((ext_vector_type(16))) float f16v;
typedef __attribute__((ext_vector_type(4))) unsigned u4v;

__device__ __forceinline__ float fast_exp2(float x) { return __builtin_amdgcn_exp2f(x); }

__device__ __forceinline__ unsigned short f2bf(float f) {
  unsigned u = __builtin_bit_cast(unsigned, f);
  u += 0x7fffu + ((u >> 16) & 1u);
  return (unsigned short)(u >> 16);
}
__device__ __forceinline__ float bf2f(unsigned short h) {
  unsigned u = ((unsigned)h) << 16;
  return __builtin_bit_cast(float, u);
}

// async global->LDS, 16B per lane; LDS dest = wave-uniform base + lane*16
__device__ __forceinline__ void glds16(const unsigned short* g, unsigned short* l) {
  __builtin_amdgcn_global_load_lds((const __attribute__((address_space(1))) void*)g,
                                   (__attribute__((address_space(3))) void*)l, 16, 0, 0);
}

// ---------------- cast x -> bf16 (vectorized) ----------------
__global__ __launch_bounds__(256) void cast_kernel(const float* __restrict__ in,
                                                   unsigned short* __restrict__ out) {
  const int idx = (blockIdx.x * 256 + threadIdx.x) * 4;
  const float4 v = *(const float4*)(in + idx);
  ushort4 o;
  o.x = f2bf(v.x); o.y = f2bf(v.y); o.z = f2bf(v.z); o.w = f2bf(v.w);
  *(ushort4*)(out + idx) = o;
}

// ---------------- transpose + cast weights: in[R][C] -> out[C][R] bf16 ----------------
__global__ __launch_bounds__(256) void transpose_cast_kernel(const float* __restrict__ in,
                                                             unsigned short* __restrict__ out,
                                                             int R, int C) {
  __shared__ float tile[32][33];
  const int c0 = blockIdx.x * 32, r0 = blockIdx.y * 32;
  const int tx = threadIdx.x, ty = threadIdx.y;
#pragma unroll
  for (int i = 0; i < 4; ++i)
    tile[ty + 8 * i][tx] = in[(size_t)(r0 + ty + 8 * i) * C + c0 + tx];
  __syncthreads();
#pragma unroll
  for (int i = 0; i < 4; ++i)
    out[(size_t)(c0 + ty + 8 * i) * R + r0 + tx] = f2bf(tile[tx][ty + 8 * i]);
}

// ---------------- transpose V: v[bh][2048][64] -> vt[bh][64][2048] (bf16) ----------
__global__ __launch_bounds__(256) void transpose_v_kernel(
    const unsigned short* __restrict__ V, unsigned short* __restrict__ Vt) {
  __shared__ alignas(16) unsigned short T[64 * 64];
  const int bh = blockIdx.y;
  const int n0 = blockIdx.x * 64;
  const int tid = threadIdx.x;
  {
    const int r = tid >> 2;
    const int seg = tid & 3;
#pragma unroll
    for (int s = 0; s < 2; ++s) {
      const int sg = seg + 4 * s;
      const sh8 v = *(const sh8*)&V[((size_t)bh * 2048 + n0 + r) * 64 + sg * 8];
      *(sh8*)&T[r * 64 + ((sg * 8) ^ ((r & 7) << 3))] = v;
    }
  }
  __syncthreads();
  const int d = tid & 63;
  const int h2 = tid >> 6;
  unsigned buf[8];
#pragma unroll
  for (int t = 0; t < 8; ++t) {
    const int n1 = h2 * 16 + 2 * t;
    const unsigned short a = T[n1 * 64 + (d ^ ((n1 & 7) << 3))];
    const unsigned short b = T[(n1 + 1) * 64 + (d ^ (((n1 + 1) & 7) << 3))];
    buf[t] = (unsigned)a | ((unsigned)b << 16);
  }
  unsigned short* dst = Vt + ((size_t)bh * 64 + d) * 2048 + n0 + h2 * 16;
  *(uint4*)dst = *(uint4*)&buf[0];
  *(uint4*)(dst + 8) = *(uint4*)&buf[4];
}

// ------- bf16 MFMA GEMM, 4-deep counted-vmcnt pipeline: C = A[M][K] @ Bt[N][K]^T -------
// LDS slot swizzle: content(row, sp) = G[row][(sp ^ ((row>>1)&3))*8]  -> 2-way banks (free).
// MODE 0: QKV epilogue -> q/k/v [B*H][N][64] bf16; Q scaled by 0.125*log2(e)
// MODE 1: proj epilogue -> out = acc + bias (fp32)
template <int MODE>
__global__ __launch_bounds__(256, 2) void gemm_bf16_kernel(
    const unsigned short* __restrict__ A,
    const unsigned short* __restrict__ Bt,
    int M, int N, int K,
    unsigned short* __restrict__ q_out, unsigned short* __restrict__ k_out,
    unsigned short* __restrict__ v_out,
    const float* __restrict__ bias, float* __restrict__ c_out) {
  __shared__ alignas(16) unsigned short As[4 * 128 * 32];
  __shared__ alignas(16) unsigned short Bs[4 * 128 * 32];
  const int tid = threadIdx.x;
  const int lane = tid & 63;
  const int wave = tid >> 6;
  const int wr = (wave >> 1) * 64;
  const int wc = (wave & 1) * 64;
  const int bm = blockIdx.x * 128;
  const int bn = blockIdx.y * 128;
  const int fr = lane & 15;
  const int kq = lane >> 4;

  f4v acc[4][4] = {};

  // staging: per wave 2 chunks of 16 rows for A and B (4 glds16/thread/stage)
  const int r16 = lane >> 2;                       // row within 16-row chunk
  const int srcsl = (lane & 3) ^ ((r16 >> 1) & 3); // pre-swizzled source slot
  const int rb0 = wave * 32, rb1 = wave * 32 + 16;

#define GSTAGE(g)                                                                            \
  {                                                                                          \
    const int _b = ((g) & 3) * 4096;                                                         \
    const int _k0 = (g) * 32;                                                                \
    glds16(&A[(size_t)(bm + rb0 + r16) * K + _k0 + srcsl * 8], &As[_b + rb0 * 32]);          \
    glds16(&A[(size_t)(bm + rb1 + r16) * K + _k0 + srcsl * 8], &As[_b + rb1 * 32]);          \
    glds16(&Bt[(size_t)(bn + rb0 + r16) * K + _k0 + srcsl * 8], &Bs[_b + rb0 * 32]);         \
    glds16(&Bt[(size_t)(bn + rb1 + r16) * K + _k0 + srcsl * 8], &Bs[_b + rb1 * 32]);         \
  }

  const int nT = K >> 5;   // 32 iters for K=1024
  GSTAGE(0);
  GSTAGE(1);

  const int rsl = (kq ^ ((fr >> 1) & 3)) * 8;      // read slot (shorts)

  for (int j = 0; j < nT; ++j) {
    const int buf = (j & 3) * 4096;
    if (j + 2 < nT) {
      GSTAGE(j + 2);
      asm volatile("s_waitcnt vmcnt(8)" ::: "memory");
    } else if (j + 1 < nT) {
      asm volatile("s_waitcnt vmcnt(4)" ::: "memory");
    } else {
      asm volatile("s_waitcnt vmcnt(0)" ::: "memory");
    }
    __builtin_amdgcn_s_barrier();

    bf8v af[4], bfv[4];
#pragma unroll
    for (int m = 0; m < 4; ++m)
      af[m] = __builtin_bit_cast(bf8v, *(const sh8*)&As[buf + (wr + m * 16 + fr) * 32 + rsl]);
#pragma unroll
    for (int n = 0; n < 4; ++n)
      bfv[n] = __builtin_bit_cast(bf8v, *(const sh8*)&Bs[buf + (wc + n * 16 + fr) * 32 + rsl]);
    __builtin_amdgcn_s_setprio(1);
#pragma unroll
    for (int m = 0; m < 4; ++m)
#pragma unroll
      for (int n = 0; n < 4; ++n)
        acc[m][n] = __builtin_amdgcn_mfma_f32_16x16x32_bf16(af[m], bfv[n], acc[m][n], 0, 0, 0);
    __builtin_amdgcn_s_setprio(0);
  }
#undef GSTAGE

#pragma unroll
  for (int m = 0; m < 4; ++m) {
#pragma unroll
    for (int n = 0; n < 4; ++n) {
#pragma unroll
      for (int i = 0; i < 4; ++i) {
        const int r = bm + wr + m * 16 + kq * 4 + i;
        const int c = bn + wc + n * 16 + fr;
        const float val = acc[m][n][i];
        if (MODE == 0) {
          const int b = r >> 11, nidx = r & 2047;
          const int which = c >> 10, rem = c & 1023;
          const int h = rem >> 6, d = rem & 63;
          const size_t off = ((size_t)((b * 16 + h) * 2048 + nidx)) * 64 + d;
          if (which == 0)      q_out[off] = f2bf(val * 0.18033688f);  // 0.125 * log2(e)
          else if (which == 1) k_out[off] = f2bf(val);
          else                 v_out[off] = f2bf(val);
        } else {
          c_out[(size_t)r * N + c] = val + bias[c];
        }
      }
    }
  }
}

// ---------------- causal flash attention: swapped QK^T, paired q-tiles, counted vmcnt ----
// Q/K: [bh][2048][64] bf16 (Q pre-scaled by 0.125*log2e). Vt: [bh][64][2048]. O: [B*2048][1024].
// 512 blocks; block = (bh, pair): q-tiles qtA=pair, qtB=15-pair sharing one KV stream.
// 4 waves x 32 q-rows per q-tile. 4-deep LDS buffers, prefetch depth 2, vmcnt(8), raw barrier.
__global__ __launch_bounds__(256, 2) void attn_kernel(
    const unsigned short* __restrict__ Q, const unsigned short* __restrict__ Kg,
    const unsigned short* __restrict__ Vtg, unsigned short* __restrict__ O) {
  __shared__ alignas(16) unsigned short Ks[4][64 * 64];
  __shared__ alignas(16) unsigned short Vts[4][64 * 64];
  const int tid = threadIdx.x;
  const int lane = tid & 63;
  const int w = tid >> 6;
  const int q31 = lane & 31, hi = lane >> 5;
  const int sw = (lane & 7) << 3;
  // XCD-aware bijective swizzle (nwg=512): 8 bh per 64-block chunk
  const int wg = (blockIdx.x & 7) * 64 + (blockIdx.x >> 3);
  const int bh = wg >> 3;
  const int pair = wg & 7;
  const int qtA = pair, qtB = 15 - pair;
  const unsigned short* Qb = Q + (size_t)bh * (2048 * 64);
  const unsigned short* Kb = Kg + (size_t)bh * (2048 * 64);
  const unsigned short* Vtb = Vtg + (size_t)bh * (64 * 2048);
  const int q0wA = qtA * 128 + w * 32;
  const int q0wB = qtB * 128 + w * 32;

  // Q B-fragments for both q-tiles: lane holds Q[q0w+q31][8hi + 16dk + t]
  bf8v qfA[4], qfB[4];
#pragma unroll
  for (int dk = 0; dk < 4; ++dk) {
    qfA[dk] = __builtin_bit_cast(bf8v, *(const sh8*)&Qb[(size_t)(q0wA + q31) * 64 + 8 * hi + 16 * dk]);
    qfB[dk] = __builtin_bit_cast(bf8v, *(const sh8*)&Qb[(size_t)(q0wB + q31) * 64 + 8 * hi + 16 * dk]);
  }

  f16v oA0 = {}, oA1 = {}, oB0 = {}, oB1 = {};
  float mA = -1e30f, lA = 0.f, mB = -1e30f, lB = 0.f;

  const int r8 = lane >> 3;
  const int gslot = (lane & 7) ^ r8;
  const int rb0 = w * 16, rb1 = w * 16 + 8;

#define STAGE(g)                                                                              \
  {                                                                                           \
    const int _b = (g) & 3;                                                                   \
    glds16(&Kb[(size_t)((g) * 64 + rb0 + r8) * 64 + gslot * 8], &Ks[_b][rb0 * 64]);           \
    glds16(&Kb[(size_t)((g) * 64 + rb1 + r8) * 64 + gslot * 8], &Ks[_b][rb1 * 64]);           \
    glds16(&Vtb[(size_t)(rb0 + r8) * 2048 + (g) * 64 + gslot * 8], &Vts[_b][rb0 * 64]);       \
    glds16(&Vtb[(size_t)(rb1 + r8) * 2048 + (g) * 64 + gslot * 8], &Vts[_b][rb1 * 64]);       \
  }

  // one KV-tile body for one q-tile (all state by reference -> static regs)
  auto body = [&](int j, int buf, int q0w, bf8v (&qf)[4], f16v& o0, f16v& o1,
                  float& m_i, float& l_i) {
    f16v s0 = {}, s1 = {};
    __builtin_amdgcn_s_setprio(1);
#pragma unroll
    for (int dk = 0; dk < 4; ++dk) {
      const int col = (8 * hi + 16 * dk) ^ sw;
      const bf8v k0 = __builtin_bit_cast(bf8v, *(const sh8*)&Ks[buf][q31 * 64 + col]);
      const bf8v k1 = __builtin_bit_cast(bf8v, *(const sh8*)&Ks[buf][(32 + q31) * 64 + col]);
      s0 = __builtin_amdgcn_mfma_f32_32x32x16_bf16(k0, qf[dk], s0, 0, 0, 0);
      s1 = __builtin_amdgcn_mfma_f32_32x32x16_bf16(k1, qf[dk], s1, 0, 0, 0);
    }
    __builtin_amdgcn_s_setprio(0);

    const int qg = q0w + q31;
    if (j * 64 + 63 > q0w) {   // diagonal region
#pragma unroll
      for (int r = 0; r < 16; ++r) {
        const int kl = j * 64 + (r & 3) + 8 * (r >> 2) + 4 * hi;
        if (kl > qg) s0[r] = -1e30f;
        if (kl + 32 > qg) s1[r] = -1e30f;
      }
    }

    float mx = -1e30f;
#pragma unroll
    for (int r = 0; r < 16; ++r) mx = fmaxf(mx, fmaxf(s0[r], s1[r]));
    mx = fmaxf(mx, __shfl_xor(mx, 32));

    if (!__all(mx - m_i <= 8.f)) {   // defer-max rare path
      const float mn = fmaxf(m_i, mx);
      const float alpha = fast_exp2(m_i - mn);
      m_i = mn;
      l_i *= alpha;
#pragma unroll
      for (int r = 0; r < 16; ++r) {
        const float ar = __shfl(alpha, (r & 3) + 8 * (r >> 2) + 4 * hi);
        o0[r] *= ar;
        o1[r] *= ar;
      }
    }

    float ps = 0.f;
#pragma unroll
    for (int r = 0; r < 16; ++r) {
      s0[r] = fast_exp2(s0[r] - m_i);
      s1[r] = fast_exp2(s1[r] - m_i);
      ps += s0[r] + s1[r];
    }
    ps += __shfl_xor(ps, 32);
    l_i += ps;

    unsigned w0[8], w1[8];
#pragma unroll
    for (int jj = 0; jj < 8; ++jj) {
      asm("v_cvt_pk_bf16_f32 %0, %1, %2" : "=v"(w0[jj]) : "v"(s0[2 * jj]), "v"(s0[2 * jj + 1]));
      asm("v_cvt_pk_bf16_f32 %0, %1, %2" : "=v"(w1[jj]) : "v"(s1[2 * jj]), "v"(s1[2 * jj + 1]));
    }

#pragma unroll
    for (int ks = 0; ks < 4; ++ks) {
      const int j0 = 4 * (ks & 1);
      unsigned x0 = (ks < 2 ? w0[j0 + 0] : w1[j0 + 0]);
      unsigned y0 = (ks < 2 ? w0[j0 + 2] : w1[j0 + 2]);
      unsigned x1 = (ks < 2 ? w0[j0 + 1] : w1[j0 + 1]);
      unsigned y1 = (ks < 2 ? w0[j0 + 3] : w1[j0 + 3]);
      asm("v_permlane32_swap_b32 %0, %1" : "+v"(x0), "+v"(y0));
      asm("v_permlane32_swap_b32 %0, %1" : "+v"(x1), "+v"(y1));
      u4v pw;
      pw[0] = x0; pw[1] = x1; pw[2] = y0; pw[3] = y1;
      const bf8v pa = __builtin_bit_cast(bf8v, pw);

      const int colv = (8 * hi + 16 * ks) ^ sw;
      const bf8v vf0 = __builtin_bit_cast(bf8v, *(const sh8*)&Vts[buf][q31 * 64 + colv]);
      const bf8v vf1 = __builtin_bit_cast(bf8v, *(const sh8*)&Vts[buf][(32 + q31) * 64 + colv]);
      __builtin_amdgcn_s_setprio(1);
      o0 = __builtin_amdgcn_mfma_f32_32x32x16_bf16(pa, vf0, o0, 0, 0, 0);
      o1 = __builtin_amdgcn_mfma_f32_32x32x16_bf16(pa, vf1, o1, 0, 0, 0);
      __builtin_amdgcn_s_setprio(0);
    }
  };

  const int b = bh >> 4, h = bh & 15;
  auto epi = [&](int q0w, f16v& o0, f16v& o1, float l_i) {
    const float rl = 1.f / l_i;
#pragma unroll
    for (int r = 0; r < 16; ++r) {
      const int cr = (r & 3) + 8 * (r >> 2) + 4 * hi;
      const float lr = __shfl(rl, cr);
      const size_t base = ((size_t)(b * 2048 + q0w + cr)) * 1024 + h * 64 + q31;
      O[base] = f2bf(o0[r] * lr);
      O[base + 32] = f2bf(o1[r] * lr);
    }
  };

  const int nA = 2 * qtA + 2;        // bodyA tiles
  const int nT = 2 * qtB + 2;        // total KV tiles (B is longer; nT > nA always)

  STAGE(0);
  STAGE(1);

  for (int j = 0; j < nT; ++j) {
    const int buf = j & 3;
    if (j + 2 < nT) {
      STAGE(j + 2);
      asm volatile("s_waitcnt vmcnt(8)" ::: "memory");
    } else if (j + 1 < nT) {
      asm volatile("s_waitcnt vmcnt(4)" ::: "memory");
    } else {
      asm volatile("s_waitcnt vmcnt(0)" ::: "memory");
    }
    __builtin_amdgcn_s_barrier();

    if (j < nA) body(j, buf, q0wA, qfA, oA0, oA1, mA, lA);
    body(j, buf, q0wB, qfB, oB0, oB1, mB, lB);

    if (j == nA - 1) epi(q0wA, oA0, oA1, lA);
  }
#undef STAGE

  epi(q0wB, oB0, oB1, lB);
}

extern "C" void kernel_launch(void* const* d_in, const int* in_sizes, int n_in,
                              void* d_out, int out_size, void* d_ws, size_t ws_size,
                              hipStream_t stream) {
  const float* x      = (const float*)d_in[0];
  const float* qkv_w  = (const float*)d_in[1];
  const float* proj_w = (const float*)d_in[2];
  const float* proj_b = (const float*)d_in[3];
  float* out = (float*)d_out;

  unsigned short* ws = (unsigned short*)d_ws;
  const size_t NE = (size_t)8192 * 1024;
  unsigned short* xb     = ws;
  unsigned short* wqkvT  = xb + NE;
  unsigned short* wprojT = wqkvT + (size_t)3072 * 1024;
  unsigned short* qb     = wprojT + (size_t)1024 * 1024;
  unsigned short* kb     = qb + NE;
  unsigned short* vb     = kb + NE;
  unsigned short* vt     = vb + NE;
  unsigned short* ab     = xb;

  cast_kernel<<<8192, 256, 0, stream>>>(x, xb);
  transpose_cast_kernel<<<dim3(96, 32), dim3(32, 8), 0, stream>>>(qkv_w, wqkvT, 1024, 3072);
  transpose_cast_kernel<<<dim3(32, 32), dim3(32, 8), 0, stream>>>(proj_w, wprojT, 1024, 1024);

  gemm_bf16_kernel<0><<<dim3(64, 24), 256, 0, stream>>>(
      xb, wqkvT, 8192, 3072, 1024, qb, kb, vb, nullptr, nullptr);

  transpose_v_kernel<<<dim3(32, 64), 256, 0, stream>>>(vb, vt);

  attn_kernel<<<512, 256, 0, stream>>>(qb, kb, vt, ab);

  gemm_bf16_kernel<1><<<dim3(64, 8), 256, 0, stream>>>(
      ab, wprojT, 8192, 1024, 1024, nullptr, nullptr, nullptr, proj_b, out);
}